// Round 1
// baseline (1366.463 us; speedup 1.0000x reference)
//
#include <hip/hip_runtime.h>
#include <cstdint>
#include <cstddef>

constexpr int N_NODES = 100000;
constexpr int N_EDGES = 20000;
constexpr int NNZ     = 1000000;

// ---------------- degree counting ----------------
__global__ void count_kernel(const int* __restrict__ ni, const int* __restrict__ ei,
                             int* __restrict__ dcnt, int* __restrict__ bcnt) {
  int i = blockIdx.x * blockDim.x + threadIdx.x;
  if (i < NNZ) {
    atomicAdd(&dcnt[ni[i]], 1);
    atomicAdd(&bcnt[ei[i]], 1);
  }
}

__global__ void invert_kernel(const int* __restrict__ cnt, float* __restrict__ inv, int n) {
  int i = blockIdx.x * blockDim.x + threadIdx.x;
  if (i < n) {
    int c = cnt[i];
    inv[i] = c > 0 ? 1.0f / (float)c : 0.0f;
  }
}

// ---------------- exclusive scan (3-kernel) ----------------
template <int BS>
__global__ void scan_block(const int* __restrict__ cnt, int n, int* __restrict__ out,
                           int* __restrict__ partials) {
  __shared__ int buf[BS];
  int tid = threadIdx.x;
  int i = blockIdx.x * BS + tid;
  int v = (i < n) ? cnt[i] : 0;
  buf[tid] = v;
  __syncthreads();
  for (int o = 1; o < BS; o <<= 1) {
    int t = (tid >= o) ? buf[tid - o] : 0;
    __syncthreads();
    buf[tid] += t;
    __syncthreads();
  }
  if (i < n) out[i] = buf[tid] - v;  // local exclusive
  if (tid == BS - 1) partials[blockIdx.x] = buf[tid];
}

__global__ void scan_partials(int* __restrict__ partials, int nb, int* __restrict__ total_out) {
  __shared__ int buf[1024];
  int tid = threadIdx.x;
  int v = (tid < nb) ? partials[tid] : 0;
  buf[tid] = v;
  __syncthreads();
  for (int o = 1; o < 1024; o <<= 1) {
    int t = (tid >= o) ? buf[tid - o] : 0;
    __syncthreads();
    buf[tid] += t;
    __syncthreads();
  }
  if (tid < nb) partials[tid] = buf[tid] - v;  // exclusive over block totals
  if (tid == 1023) *total_out = buf[1023];     // grand total (= NNZ)
}

__global__ void scan_add(int* __restrict__ out, int n, const int* __restrict__ partials) {
  int i = blockIdx.x * blockDim.x + threadIdx.x;
  if (i < n) out[i] += partials[blockIdx.x];
}

// ---------------- CSR fill (atomic cursors) ----------------
__global__ void fill_kernel(const int* __restrict__ ni, const int* __restrict__ ei,
                            const int* __restrict__ noff, const int* __restrict__ eoff,
                            int* __restrict__ ncur, int* __restrict__ ecur,
                            int* __restrict__ nedges, int* __restrict__ enodes) {
  int i = blockIdx.x * blockDim.x + threadIdx.x;
  if (i < NNZ) {
    int n = ni[i], e = ei[i];
    int p = atomicAdd(&ecur[e], 1);
    enodes[eoff[e] + p] = n;
    int q = atomicAdd(&ncur[n], 1);
    nedges[noff[n] + q] = e;
  }
}

// ---------------- f32 tiled GEMM: C[M,N] = A[M,K] @ W[K,N] ----------------
// 256 threads, BM=BN=64, BK=16, per-thread 4x4. K must be a multiple of 16.
__global__ __launch_bounds__(256) void gemm64(const float* __restrict__ A,
                                              const float* __restrict__ W,
                                              float* __restrict__ C,
                                              int M, int K, int N) {
  __shared__ float As[16][65];
  __shared__ float Ws[16][64];
  const int bm = blockIdx.x * 64;
  const int bn = blockIdx.y * 64;
  const int tid = threadIdx.x;
  const int tx = tid & 15;
  const int ty = tid >> 4;
  float acc[4][4] = {};

  for (int k0 = 0; k0 < K; k0 += 16) {
    {
      int kk = tid & 15;
      int r0 = tid >> 4;
#pragma unroll
      for (int p = 0; p < 4; ++p) {
        int row = r0 + p * 16;
        int gr = bm + row;
        As[kk][row] = (gr < M) ? A[(size_t)gr * K + k0 + kk] : 0.0f;
      }
    }
    {
      int c = tid & 63;
      int r0 = tid >> 6;
#pragma unroll
      for (int p = 0; p < 4; ++p) {
        int kr = r0 + p * 4;
        int gc = bn + c;
        Ws[kr][c] = (gc < N) ? W[(size_t)(k0 + kr) * N + gc] : 0.0f;
      }
    }
    __syncthreads();
#pragma unroll
    for (int k = 0; k < 16; ++k) {
      float a[4], b[4];
#pragma unroll
      for (int j = 0; j < 4; ++j) a[j] = As[k][ty * 4 + j];
#pragma unroll
      for (int j = 0; j < 4; ++j) b[j] = Ws[k][tx * 4 + j];
#pragma unroll
      for (int i2 = 0; i2 < 4; ++i2)
#pragma unroll
        for (int j2 = 0; j2 < 4; ++j2) acc[i2][j2] += a[i2] * b[j2];
    }
    __syncthreads();
  }

#pragma unroll
  for (int i2 = 0; i2 < 4; ++i2) {
    int gr = bm + ty * 4 + i2;
    if (gr < M) {
#pragma unroll
      for (int j2 = 0; j2 < 4; ++j2) {
        int gc = bn + tx * 4 + j2;
        if (gc < N) C[(size_t)gr * N + gc] = acc[i2][j2];
      }
    }
  }
}

// ---------------- segment reductions, F=256 (one wave per segment) ----------------
__global__ __launch_bounds__(256) void edge_reduce256(const float* __restrict__ xw,
                                                      const int* __restrict__ eoff,
                                                      const int* __restrict__ enodes,
                                                      const float* __restrict__ binv,
                                                      float* __restrict__ m) {
  int w = (blockIdx.x * blockDim.x + threadIdx.x) >> 6;
  int lane = threadIdx.x & 63;
  if (w >= N_EDGES) return;
  int s = eoff[w], t = eoff[w + 1];
  float ax = 0.f, ay = 0.f, az = 0.f, aw = 0.f;
  for (int j = s; j < t; ++j) {
    int nd = enodes[j];
    float4 v = *reinterpret_cast<const float4*>(&xw[(size_t)nd * 256 + lane * 4]);
    ax += v.x; ay += v.y; az += v.z; aw += v.w;
  }
  float bv = binv[w];
  float4 r;
  r.x = ax * bv; r.y = ay * bv; r.z = az * bv; r.w = aw * bv;
  *reinterpret_cast<float4*>(&m[(size_t)w * 256 + lane * 4]) = r;
}

__device__ __forceinline__ float elu_f(float x) { return x > 0.f ? x : expm1f(x); }

template <bool ACT>
__global__ __launch_bounds__(256) void node_reduce256(const float* __restrict__ m,
                                                      const int* __restrict__ noff,
                                                      const int* __restrict__ nedges,
                                                      const float* __restrict__ dinv,
                                                      const float* __restrict__ bias,
                                                      float* __restrict__ out) {
  int w = (blockIdx.x * blockDim.x + threadIdx.x) >> 6;
  int lane = threadIdx.x & 63;
  if (w >= N_NODES) return;
  int s = noff[w], t = noff[w + 1];
  float ax = 0.f, ay = 0.f, az = 0.f, aw = 0.f;
  for (int j = s; j < t; ++j) {
    int ed = nedges[j];
    float4 v = *reinterpret_cast<const float4*>(&m[(size_t)ed * 256 + lane * 4]);
    ax += v.x; ay += v.y; az += v.z; aw += v.w;
  }
  float dv = dinv[w];
  float4 b4 = *reinterpret_cast<const float4*>(&bias[lane * 4]);
  float4 r;
  r.x = ax * dv + b4.x;
  r.y = ay * dv + b4.y;
  r.z = az * dv + b4.z;
  r.w = aw * dv + b4.w;
  if (ACT) { r.x = elu_f(r.x); r.y = elu_f(r.y); r.z = elu_f(r.z); r.w = elu_f(r.w); }
  *reinterpret_cast<float4*>(&out[(size_t)w * 256 + lane * 4]) = r;
}

// ---------------- segment reductions, F=40 (one wave per segment, lanes 0..39) ----------------
__global__ __launch_bounds__(256) void edge_reduce40(const float* __restrict__ xw,
                                                     const int* __restrict__ eoff,
                                                     const int* __restrict__ enodes,
                                                     const float* __restrict__ binv,
                                                     float* __restrict__ m) {
  int w = (blockIdx.x * blockDim.x + threadIdx.x) >> 6;
  int lane = threadIdx.x & 63;
  if (w >= N_EDGES || lane >= 40) return;
  int s = eoff[w], t = eoff[w + 1];
  float acc = 0.f;
  for (int j = s; j < t; ++j) {
    int nd = enodes[j];
    acc += xw[(size_t)nd * 40 + lane];
  }
  m[(size_t)w * 40 + lane] = acc * binv[w];
}

__global__ __launch_bounds__(256) void node_reduce40(const float* __restrict__ m,
                                                     const int* __restrict__ noff,
                                                     const int* __restrict__ nedges,
                                                     const float* __restrict__ dinv,
                                                     const float* __restrict__ bias,
                                                     float* __restrict__ out) {
  int w = (blockIdx.x * blockDim.x + threadIdx.x) >> 6;
  int lane = threadIdx.x & 63;
  if (w >= N_NODES || lane >= 40) return;
  int s = noff[w], t = noff[w + 1];
  float acc = 0.f;
  for (int j = s; j < t; ++j) {
    int ed = nedges[j];
    acc += m[(size_t)ed * 40 + lane];
  }
  out[(size_t)w * 40 + lane] = acc * dinv[w] + bias[lane];
}

// ---------------- launch ----------------
extern "C" void kernel_launch(void* const* d_in, const int* in_sizes, int n_in,
                              void* d_out, int out_size, void* d_ws, size_t ws_size,
                              hipStream_t stream) {
  const float* x  = (const float*)d_in[0];
  const int*   ni = (const int*)d_in[1];
  const int*   ei = (const int*)d_in[2];
  const float* W1 = (const float*)d_in[3];
  const float* b1 = (const float*)d_in[4];
  const float* W2 = (const float*)d_in[5];
  const float* b2 = (const float*)d_in[6];
  const float* W3 = (const float*)d_in[7];
  const float* b3 = (const float*)d_in[8];
  float* out = (float*)d_out;

  char* wsp = (char*)d_ws;
  auto alloc = [&](size_t bytes) -> void* {
    void* p = (void*)wsp;
    wsp += (bytes + 255) & ~(size_t)255;
    return p;
  };
  float* bufA  = (float*)alloc((size_t)N_NODES * 256 * 4);  // 102.4 MB
  float* bufB  = (float*)alloc((size_t)N_NODES * 256 * 4);  // 102.4 MB
  float* mbuf  = (float*)alloc((size_t)N_EDGES * 256 * 4);  // 20.5 MB
  int* dcnt    = (int*)alloc((size_t)N_NODES * 4);
  int* bcnt    = (int*)alloc((size_t)N_EDGES * 4);
  int* ncur    = (int*)alloc((size_t)N_NODES * 4);
  int* ecur    = (int*)alloc((size_t)N_EDGES * 4);
  int* noff    = (int*)alloc((size_t)(N_NODES + 1) * 4);
  int* eoff    = (int*)alloc((size_t)(N_EDGES + 1) * 4);
  int* npart   = (int*)alloc((size_t)((N_NODES + 255) / 256) * 4);
  int* epart   = (int*)alloc((size_t)((N_EDGES + 255) / 256) * 4);
  int* nedges  = (int*)alloc((size_t)NNZ * 4);  // 4 MB
  int* enodes  = (int*)alloc((size_t)NNZ * 4);  // 4 MB
  float* dinv  = (float*)alloc((size_t)N_NODES * 4);
  float* binv  = (float*)alloc((size_t)N_EDGES * 4);

  hipMemsetAsync(dcnt, 0, (size_t)N_NODES * 4, stream);
  hipMemsetAsync(bcnt, 0, (size_t)N_EDGES * 4, stream);
  hipMemsetAsync(ncur, 0, (size_t)N_NODES * 4, stream);
  hipMemsetAsync(ecur, 0, (size_t)N_EDGES * 4, stream);

  count_kernel<<<(NNZ + 255) / 256, 256, 0, stream>>>(ni, ei, dcnt, bcnt);
  invert_kernel<<<(N_NODES + 255) / 256, 256, 0, stream>>>(dcnt, dinv, N_NODES);
  invert_kernel<<<(N_EDGES + 255) / 256, 256, 0, stream>>>(bcnt, binv, N_EDGES);

  const int nb_n = (N_NODES + 255) / 256;  // 391
  const int nb_e = (N_EDGES + 255) / 256;  // 79
  scan_block<256><<<nb_n, 256, 0, stream>>>(dcnt, N_NODES, noff, npart);
  scan_block<256><<<nb_e, 256, 0, stream>>>(bcnt, N_EDGES, eoff, epart);
  scan_partials<<<1, 1024, 0, stream>>>(npart, nb_n, &noff[N_NODES]);
  scan_partials<<<1, 1024, 0, stream>>>(epart, nb_e, &eoff[N_EDGES]);
  scan_add<<<nb_n, 256, 0, stream>>>(noff, N_NODES, npart);
  scan_add<<<nb_e, 256, 0, stream>>>(eoff, N_EDGES, epart);

  fill_kernel<<<(NNZ + 255) / 256, 256, 0, stream>>>(ni, ei, noff, eoff, ncur, ecur, nedges, enodes);

  const int eblocks = (N_EDGES * 64 + 255) / 256;   // 5000
  const int nblocks = (N_NODES * 64 + 255) / 256;   // 25000

  // Layer 1: x[100000,128] @ W1[128,256]
  gemm64<<<dim3((N_NODES + 63) / 64, 4), 256, 0, stream>>>(x, W1, bufA, N_NODES, 128, 256);
  edge_reduce256<<<eblocks, 256, 0, stream>>>(bufA, eoff, enodes, binv, mbuf);
  node_reduce256<true><<<nblocks, 256, 0, stream>>>(mbuf, noff, nedges, dinv, b1, bufB);

  // Layer 2: h1 @ W2[256,256]
  gemm64<<<dim3((N_NODES + 63) / 64, 4), 256, 0, stream>>>(bufB, W2, bufA, N_NODES, 256, 256);
  edge_reduce256<<<eblocks, 256, 0, stream>>>(bufA, eoff, enodes, binv, mbuf);
  node_reduce256<true><<<nblocks, 256, 0, stream>>>(mbuf, noff, nedges, dinv, b2, bufB);

  // Layer 3: h2 @ W3[256,40], no activation, write d_out
  gemm64<<<dim3((N_NODES + 63) / 64, 1), 256, 0, stream>>>(bufB, W3, bufA, N_NODES, 256, 40);
  edge_reduce40<<<eblocks, 256, 0, stream>>>(bufA, eoff, enodes, binv, mbuf);
  node_reduce40<<<nblocks, 256, 0, stream>>>(mbuf, noff, nedges, dinv, b3, out);
}

// Round 2
// 1329.433 us; speedup vs baseline: 1.0279x; 1.0279x over previous
//
#include <hip/hip_runtime.h>
#include <cstdint>
#include <cstddef>

constexpr int N_NODES = 100000;
constexpr int N_EDGES = 20000;
constexpr int NNZ     = 1000000;
constexpr int NPAD    = 100096;  // 782 * 128

typedef __attribute__((ext_vector_type(8))) __bf16 bf16x8;
typedef __attribute__((ext_vector_type(4))) float f32x4;
typedef __attribute__((ext_vector_type(4))) unsigned int uint4v;

// ---------------- bf16 split helpers (RNE) ----------------
__device__ __forceinline__ unsigned short bf16_rne(float v) {
  unsigned u = __builtin_bit_cast(unsigned, v);
  return (unsigned short)((u + 0x7FFFu + ((u >> 16) & 1u)) >> 16);
}
__device__ __forceinline__ void split2(float v, unsigned short& h, unsigned short& l) {
  unsigned u = __builtin_bit_cast(unsigned, v);
  unsigned hb = (u + 0x7FFFu + ((u >> 16) & 1u)) & 0xFFFF0000u;
  h = (unsigned short)(hb >> 16);
  float lo = v - __builtin_bit_cast(float, hb);
  l = bf16_rne(lo);
}
__device__ __forceinline__ float elu_f(float x) { return x > 0.f ? x : expm1f(x); }

// ---------------- degree counting ----------------
__global__ void count_kernel(const int* __restrict__ ni, const int* __restrict__ ei,
                             int* __restrict__ dcnt, int* __restrict__ bcnt) {
  int i = blockIdx.x * blockDim.x + threadIdx.x;
  if (i < NNZ) {
    atomicAdd(&dcnt[ni[i]], 1);
    atomicAdd(&bcnt[ei[i]], 1);
  }
}

__global__ void invert_kernel(const int* __restrict__ cnt, float* __restrict__ inv, int n) {
  int i = blockIdx.x * blockDim.x + threadIdx.x;
  if (i < n) {
    int c = cnt[i];
    inv[i] = c > 0 ? 1.0f / (float)c : 0.0f;
  }
}

// ---------------- exclusive scan (3-kernel) ----------------
template <int BS>
__global__ void scan_block(const int* __restrict__ cnt, int n, int* __restrict__ out,
                           int* __restrict__ partials) {
  __shared__ int buf[BS];
  int tid = threadIdx.x;
  int i = blockIdx.x * BS + tid;
  int v = (i < n) ? cnt[i] : 0;
  buf[tid] = v;
  __syncthreads();
  for (int o = 1; o < BS; o <<= 1) {
    int t = (tid >= o) ? buf[tid - o] : 0;
    __syncthreads();
    buf[tid] += t;
    __syncthreads();
  }
  if (i < n) out[i] = buf[tid] - v;
  if (tid == BS - 1) partials[blockIdx.x] = buf[tid];
}

__global__ void scan_partials(int* __restrict__ partials, int nb, int* __restrict__ total_out) {
  __shared__ int buf[1024];
  int tid = threadIdx.x;
  int v = (tid < nb) ? partials[tid] : 0;
  buf[tid] = v;
  __syncthreads();
  for (int o = 1; o < 1024; o <<= 1) {
    int t = (tid >= o) ? buf[tid - o] : 0;
    __syncthreads();
    buf[tid] += t;
    __syncthreads();
  }
  if (tid < nb) partials[tid] = buf[tid] - v;
  if (tid == 1023) *total_out = buf[1023];
}

__global__ void scan_add(int* __restrict__ out, int n, const int* __restrict__ partials) {
  int i = blockIdx.x * blockDim.x + threadIdx.x;
  if (i < n) out[i] += partials[blockIdx.x];
}

// ---------------- CSR fill (atomic cursors) ----------------
__global__ void fill_kernel(const int* __restrict__ ni, const int* __restrict__ ei,
                            const int* __restrict__ noff, const int* __restrict__ eoff,
                            int* __restrict__ ncur, int* __restrict__ ecur,
                            int* __restrict__ nedges, int* __restrict__ enodes) {
  int i = blockIdx.x * blockDim.x + threadIdx.x;
  if (i < NNZ) {
    int n = ni[i], e = ei[i];
    int p = atomicAdd(&ecur[e], 1);
    enodes[eoff[e] + p] = n;
    int q = atomicAdd(&ncur[n], 1);
    nedges[noff[n] + q] = e;
  }
}

// ---------------- W split+transpose: W[K][N] f32 -> Wt_h/Wt_l [NP][K] bf16 ----------------
__global__ void wsplit_t(const float* __restrict__ W, int K, int N, int NP,
                         unsigned short* __restrict__ Th, unsigned short* __restrict__ Tl) {
  int i = blockIdx.x * 256 + threadIdx.x;
  if (i >= NP * K) return;
  int n = i / K, k = i - n * K;
  float v = (n < N) ? W[(size_t)k * N + n] : 0.0f;
  unsigned short h, l;
  split2(v, h, l);
  Th[i] = h;
  Tl[i] = l;
}

// ---------------- split-bf16 MFMA GEMM ----------------
// C[M, NFRAG*16] = A[M,K] @ B[K, NFRAG*16], A given pre-split (Ah+Al), B pre-split
// and transposed (Bh/Bl are [NFRAG*16][K] row-major = B columns).
// Block: 256 thr = 4 waves; wave handles 32 rows x all cols. Grid.x = NPAD/128.
// EPI 0: write f32 to outF (width ncols, col-masked). EPI 1: v=elu(v+bias[col]),
// split, write bf16 hi/lo at stride NFRAG*16.
template <int NFRAG, int EPI>
__global__ __launch_bounds__(256) void gemm_split(
    const unsigned short* __restrict__ Ah, const unsigned short* __restrict__ Al,
    const unsigned short* __restrict__ Bh, const unsigned short* __restrict__ Bl,
    int K, const float* __restrict__ bias, float* __restrict__ outF,
    unsigned short* __restrict__ outH, unsigned short* __restrict__ outL, int ncols) {
  const int wave = threadIdx.x >> 6;
  const int lane = threadIdx.x & 63;
  const int r = lane & 15;
  const int kb = (lane >> 4) * 8;
  const int rowbase = blockIdx.x * 128 + wave * 32;

  f32x4 acc[2][NFRAG] = {};

  for (int k0 = 0; k0 < K; k0 += 32) {
    size_t base0 = (size_t)(rowbase + r) * K + (k0 + kb);
    size_t base1 = (size_t)(rowbase + 16 + r) * K + (k0 + kb);
    bf16x8 ah0 = __builtin_bit_cast(bf16x8, *(const uint4v*)(Ah + base0));
    bf16x8 ah1 = __builtin_bit_cast(bf16x8, *(const uint4v*)(Ah + base1));
    bf16x8 al0 = __builtin_bit_cast(bf16x8, *(const uint4v*)(Al + base0));
    bf16x8 al1 = __builtin_bit_cast(bf16x8, *(const uint4v*)(Al + base1));
#pragma unroll
    for (int c = 0; c < NFRAG; ++c) {
      size_t bb = (size_t)(c * 16 + r) * K + (k0 + kb);
      bf16x8 bh = __builtin_bit_cast(bf16x8, *(const uint4v*)(Bh + bb));
      bf16x8 bl = __builtin_bit_cast(bf16x8, *(const uint4v*)(Bl + bb));
      acc[0][c] = __builtin_amdgcn_mfma_f32_16x16x32_bf16(ah0, bh, acc[0][c], 0, 0, 0);
      acc[1][c] = __builtin_amdgcn_mfma_f32_16x16x32_bf16(ah1, bh, acc[1][c], 0, 0, 0);
      acc[0][c] = __builtin_amdgcn_mfma_f32_16x16x32_bf16(ah0, bl, acc[0][c], 0, 0, 0);
      acc[1][c] = __builtin_amdgcn_mfma_f32_16x16x32_bf16(ah1, bl, acc[1][c], 0, 0, 0);
      acc[0][c] = __builtin_amdgcn_mfma_f32_16x16x32_bf16(al0, bh, acc[0][c], 0, 0, 0);
      acc[1][c] = __builtin_amdgcn_mfma_f32_16x16x32_bf16(al1, bh, acc[1][c], 0, 0, 0);
    }
  }

#pragma unroll
  for (int rg = 0; rg < 2; ++rg) {
#pragma unroll
    for (int c = 0; c < NFRAG; ++c) {
      int col = c * 16 + r;
#pragma unroll
      for (int i = 0; i < 4; ++i) {
        int row = rowbase + rg * 16 + (lane >> 4) * 4 + i;
        if (row >= N_NODES) continue;
        float v = acc[rg][c][i];
        if (EPI == 1) {
          v += bias[col];
          v = elu_f(v);
          unsigned short h, l;
          split2(v, h, l);
          size_t o = (size_t)row * (NFRAG * 16) + col;
          outH[o] = h;
          outL[o] = l;
        } else {
          if (col < ncols) outF[(size_t)row * ncols + col] = v;
        }
      }
    }
  }
}

// ---------------- segment reductions ----------------
// F=128: one wave per segment, float2 per lane
__global__ __launch_bounds__(256) void edge_reduce128(const float* __restrict__ x,
                                                      const int* __restrict__ eoff,
                                                      const int* __restrict__ enodes,
                                                      const float* __restrict__ binv,
                                                      float* __restrict__ m) {
  int w = (blockIdx.x * blockDim.x + threadIdx.x) >> 6;
  int lane = threadIdx.x & 63;
  if (w >= N_EDGES) return;
  int s = eoff[w], t = eoff[w + 1];
  float ax = 0.f, ay = 0.f;
  for (int j = s; j < t; ++j) {
    int nd = enodes[j];
    float2 v = *reinterpret_cast<const float2*>(&x[(size_t)nd * 128 + lane * 2]);
    ax += v.x;
    ay += v.y;
  }
  float bv = binv[w];
  float2 rr;
  rr.x = ax * bv;
  rr.y = ay * bv;
  *reinterpret_cast<float2*>(&m[(size_t)w * 128 + lane * 2]) = rr;
}

__global__ __launch_bounds__(256) void node_reduce128_split(const float* __restrict__ m,
                                                            const int* __restrict__ noff,
                                                            const int* __restrict__ nedges,
                                                            const float* __restrict__ dinv,
                                                            unsigned short* __restrict__ Ah,
                                                            unsigned short* __restrict__ Al) {
  int w = (blockIdx.x * blockDim.x + threadIdx.x) >> 6;
  int lane = threadIdx.x & 63;
  if (w >= N_NODES) return;
  int s = noff[w], t = noff[w + 1];
  float ax = 0.f, ay = 0.f;
  for (int j = s; j < t; ++j) {
    int ed = nedges[j];
    float2 v = *reinterpret_cast<const float2*>(&m[(size_t)ed * 128 + lane * 2]);
    ax += v.x;
    ay += v.y;
  }
  float dv = dinv[w];
  ax *= dv;
  ay *= dv;
  unsigned short h0, l0, h1, l1;
  split2(ax, h0, l0);
  split2(ay, h1, l1);
  unsigned ph = (unsigned)h0 | ((unsigned)h1 << 16);
  unsigned pl = (unsigned)l0 | ((unsigned)l1 << 16);
  *reinterpret_cast<unsigned*>(&Ah[(size_t)w * 128 + lane * 2]) = ph;
  *reinterpret_cast<unsigned*>(&Al[(size_t)w * 128 + lane * 2]) = pl;
}

// F=256: one wave per segment, float4 per lane
__global__ __launch_bounds__(256) void edge_reduce256(const float* __restrict__ xw,
                                                      const int* __restrict__ eoff,
                                                      const int* __restrict__ enodes,
                                                      const float* __restrict__ binv,
                                                      float* __restrict__ m) {
  int w = (blockIdx.x * blockDim.x + threadIdx.x) >> 6;
  int lane = threadIdx.x & 63;
  if (w >= N_EDGES) return;
  int s = eoff[w], t = eoff[w + 1];
  float ax = 0.f, ay = 0.f, az = 0.f, aw = 0.f;
  for (int j = s; j < t; ++j) {
    int nd = enodes[j];
    float4 v = *reinterpret_cast<const float4*>(&xw[(size_t)nd * 256 + lane * 4]);
    ax += v.x;
    ay += v.y;
    az += v.z;
    aw += v.w;
  }
  float bv = binv[w];
  float4 rr;
  rr.x = ax * bv;
  rr.y = ay * bv;
  rr.z = az * bv;
  rr.w = aw * bv;
  *reinterpret_cast<float4*>(&m[(size_t)w * 256 + lane * 4]) = rr;
}

__global__ __launch_bounds__(256) void node_reduce256_split_elu(
    const float* __restrict__ m, const int* __restrict__ noff,
    const int* __restrict__ nedges, const float* __restrict__ dinv,
    const float* __restrict__ bias, unsigned short* __restrict__ Ah,
    unsigned short* __restrict__ Al) {
  int w = (blockIdx.x * blockDim.x + threadIdx.x) >> 6;
  int lane = threadIdx.x & 63;
  if (w >= N_NODES) return;
  int s = noff[w], t = noff[w + 1];
  float ax = 0.f, ay = 0.f, az = 0.f, aw = 0.f;
  for (int j = s; j < t; ++j) {
    int ed = nedges[j];
    float4 v = *reinterpret_cast<const float4*>(&m[(size_t)ed * 256 + lane * 4]);
    ax += v.x;
    ay += v.y;
    az += v.z;
    aw += v.w;
  }
  float dv = dinv[w];
  float4 b4 = *reinterpret_cast<const float4*>(&bias[lane * 4]);
  float v0 = elu_f(ax * dv + b4.x);
  float v1 = elu_f(ay * dv + b4.y);
  float v2 = elu_f(az * dv + b4.z);
  float v3 = elu_f(aw * dv + b4.w);
  unsigned short h0, l0, h1, l1, h2, l2, h3, l3;
  split2(v0, h0, l0);
  split2(v1, h1, l1);
  split2(v2, h2, l2);
  split2(v3, h3, l3);
  uint2 ph, pl;
  ph.x = (unsigned)h0 | ((unsigned)h1 << 16);
  ph.y = (unsigned)h2 | ((unsigned)h3 << 16);
  pl.x = (unsigned)l0 | ((unsigned)l1 << 16);
  pl.y = (unsigned)l2 | ((unsigned)l3 << 16);
  *reinterpret_cast<uint2*>(&Ah[(size_t)w * 256 + lane * 4]) = ph;
  *reinterpret_cast<uint2*>(&Al[(size_t)w * 256 + lane * 4]) = pl;
}

// F=40: lanes 0..39 active
__global__ __launch_bounds__(256) void edge_reduce40(const float* __restrict__ xw,
                                                     const int* __restrict__ eoff,
                                                     const int* __restrict__ enodes,
                                                     const float* __restrict__ binv,
                                                     float* __restrict__ m) {
  int w = (blockIdx.x * blockDim.x + threadIdx.x) >> 6;
  int lane = threadIdx.x & 63;
  if (w >= N_EDGES || lane >= 40) return;
  int s = eoff[w], t = eoff[w + 1];
  float acc = 0.f;
  for (int j = s; j < t; ++j) {
    int nd = enodes[j];
    acc += xw[(size_t)nd * 40 + lane];
  }
  m[(size_t)w * 40 + lane] = acc * binv[w];
}

__global__ __launch_bounds__(256) void node_reduce40(const float* __restrict__ m,
                                                     const int* __restrict__ noff,
                                                     const int* __restrict__ nedges,
                                                     const float* __restrict__ dinv,
                                                     const float* __restrict__ bias,
                                                     float* __restrict__ out) {
  int w = (blockIdx.x * blockDim.x + threadIdx.x) >> 6;
  int lane = threadIdx.x & 63;
  if (w >= N_NODES || lane >= 40) return;
  int s = noff[w], t = noff[w + 1];
  float acc = 0.f;
  for (int j = s; j < t; ++j) {
    int ed = nedges[j];
    acc += m[(size_t)ed * 40 + lane];
  }
  out[(size_t)w * 40 + lane] = acc * dinv[w] + bias[lane];
}

// ---------------- launch ----------------
extern "C" void kernel_launch(void* const* d_in, const int* in_sizes, int n_in,
                              void* d_out, int out_size, void* d_ws, size_t ws_size,
                              hipStream_t stream) {
  const float* x  = (const float*)d_in[0];
  const int*   ni = (const int*)d_in[1];
  const int*   ei = (const int*)d_in[2];
  const float* W1 = (const float*)d_in[3];
  const float* b1 = (const float*)d_in[4];
  const float* W2 = (const float*)d_in[5];
  const float* b2 = (const float*)d_in[6];
  const float* W3 = (const float*)d_in[7];
  const float* b3 = (const float*)d_in[8];
  float* out = (float*)d_out;

  char* base = (char*)d_ws;
  size_t off = 0;
  auto take = [&](size_t bytes) -> char* {
    char* p = base + off;
    off += (bytes + 255) & ~(size_t)255;
    return p;
  };

  // CSR region (live for entire call)
  int* dcnt   = (int*)take((size_t)N_NODES * 4);
  int* bcnt   = (int*)take((size_t)N_EDGES * 4);
  int* ncur   = (int*)take((size_t)N_NODES * 4);
  int* ecur   = (int*)take((size_t)N_EDGES * 4);
  int* noff   = (int*)take((size_t)(N_NODES + 1) * 4);
  int* eoff   = (int*)take((size_t)(N_EDGES + 1) * 4);
  int* npart  = (int*)take((size_t)((N_NODES + 255) / 256) * 4);
  int* epart  = (int*)take((size_t)((N_EDGES + 255) / 256) * 4);
  int* nedges = (int*)take((size_t)NNZ * 4);
  int* enodes = (int*)take((size_t)NNZ * 4);
  float* dinv = (float*)take((size_t)N_NODES * 4);
  float* binv = (float*)take((size_t)N_EDGES * 4);

  // W splits (live entire call)
  unsigned short* W1th = (unsigned short*)take((size_t)256 * 128 * 2);
  unsigned short* W1tl = (unsigned short*)take((size_t)256 * 128 * 2);
  unsigned short* W2th = (unsigned short*)take((size_t)256 * 256 * 2);
  unsigned short* W2tl = (unsigned short*)take((size_t)256 * 256 * 2);
  unsigned short* W3th = (unsigned short*)take((size_t)48 * 256 * 2);
  unsigned short* W3tl = (unsigned short*)take((size_t)48 * 256 * 2);

  // Big regions with liveness-based aliasing
  const size_t A2B = (size_t)NPAD * 256 * 2;  // 51,249,152 B (one bf16 [NPAD][256])
  const size_t A1B = (size_t)NPAD * 128 * 2;  // 25,624,576 B
  char* R2 = take(2 * A2B);
  char* R3 = take(2 * A2B);

  // R2: [A2h | A2l] (gemm1 out, gemm2 in) -> then m256 in A2l slot, t3+m40 in A2h slot
  unsigned short* A2h = (unsigned short*)R2;
  unsigned short* A2l = (unsigned short*)(R2 + A2B);
  float* m256 = (float*)(R2 + A2B);                 // 20.48 MB, after gemm2
  float* t3   = (float*)R2;                         // 16 MB, after gemm2
  float* m40  = (float*)(R2 + 16000000);            // 3.2 MB (16e6 is 256-aligned)

  // R3: [m128 | A1h | A1l] early -> t2 (gemm2 out) -> [A3h | A3l]
  float* m128 = (float*)R3;                         // 10.24 MB
  unsigned short* A1h = (unsigned short*)(R3 + 10240000);
  unsigned short* A1l = (unsigned short*)(R3 + 10240000 + A1B);
  float* t2 = (float*)R3;                           // 102.4 MB
  unsigned short* A3h = (unsigned short*)R3;
  unsigned short* A3l = (unsigned short*)(R3 + A2B);

  // ---- CSR build ----
  hipMemsetAsync(dcnt, 0, (size_t)N_NODES * 4, stream);
  hipMemsetAsync(bcnt, 0, (size_t)N_EDGES * 4, stream);
  hipMemsetAsync(ncur, 0, (size_t)N_NODES * 4, stream);
  hipMemsetAsync(ecur, 0, (size_t)N_EDGES * 4, stream);

  count_kernel<<<(NNZ + 255) / 256, 256, 0, stream>>>(ni, ei, dcnt, bcnt);
  invert_kernel<<<(N_NODES + 255) / 256, 256, 0, stream>>>(dcnt, dinv, N_NODES);
  invert_kernel<<<(N_EDGES + 255) / 256, 256, 0, stream>>>(bcnt, binv, N_EDGES);

  const int nb_n = (N_NODES + 255) / 256;
  const int nb_e = (N_EDGES + 255) / 256;
  scan_block<256><<<nb_n, 256, 0, stream>>>(dcnt, N_NODES, noff, npart);
  scan_block<256><<<nb_e, 256, 0, stream>>>(bcnt, N_EDGES, eoff, epart);
  scan_partials<<<1, 1024, 0, stream>>>(npart, nb_n, &noff[N_NODES]);
  scan_partials<<<1, 1024, 0, stream>>>(epart, nb_e, &eoff[N_EDGES]);
  scan_add<<<nb_n, 256, 0, stream>>>(noff, N_NODES, npart);
  scan_add<<<nb_e, 256, 0, stream>>>(eoff, N_EDGES, epart);

  fill_kernel<<<(NNZ + 255) / 256, 256, 0, stream>>>(ni, ei, noff, eoff, ncur, ecur, nedges, enodes);

  // ---- W pre-split (transposed) ----
  wsplit_t<<<(256 * 128 + 255) / 256, 256, 0, stream>>>(W1, 128, 256, 256, W1th, W1tl);
  wsplit_t<<<(256 * 256 + 255) / 256, 256, 0, stream>>>(W2, 256, 256, 256, W2th, W2tl);
  wsplit_t<<<(48 * 256 + 255) / 256, 256, 0, stream>>>(W3, 256, 40, 48, W3th, W3tl);

  const int eblocks = (N_EDGES * 64 + 255) / 256;  // 5000
  const int nblocks = (N_NODES * 64 + 255) / 256;  // 25000
  const int gblocks = NPAD / 128;                  // 782

  // ---- Layer 1: agg = Dinv H Binv H^T x  (F=128), then h1 = elu(agg@W1 + b1) ----
  edge_reduce128<<<eblocks, 256, 0, stream>>>(x, eoff, enodes, binv, m128);
  node_reduce128_split<<<nblocks, 256, 0, stream>>>(m128, noff, nedges, dinv, A1h, A1l);
  gemm_split<16, 1><<<gblocks, 256, 0, stream>>>(A1h, A1l, W1th, W1tl, 128, b1,
                                                 nullptr, A2h, A2l, 256);

  // ---- Layer 2: t2 = h1@W2 ; h2 = elu(Dinv H Binv H^T t2 + b2) ----
  gemm_split<16, 0><<<gblocks, 256, 0, stream>>>(A2h, A2l, W2th, W2tl, 256, nullptr,
                                                 t2, nullptr, nullptr, 256);
  edge_reduce256<<<eblocks, 256, 0, stream>>>(t2, eoff, enodes, binv, m256);
  node_reduce256_split_elu<<<nblocks, 256, 0, stream>>>(m256, noff, nedges, dinv, b2, A3h, A3l);

  // ---- Layer 3: t3 = h2@W3 ; out = Dinv H Binv H^T t3 + b3 ----
  gemm_split<3, 0><<<gblocks, 256, 0, stream>>>(A3h, A3l, W3th, W3tl, 256, nullptr,
                                                t3, nullptr, nullptr, 40);
  edge_reduce40<<<eblocks, 256, 0, stream>>>(t3, eoff, enodes, binv, m40);
  node_reduce40<<<nblocks, 256, 0, stream>>>(m40, noff, nedges, dinv, b3, out);
}

// Round 4
// 1067.130 us; speedup vs baseline: 1.2805x; 1.2458x over previous
//
#include <hip/hip_runtime.h>
#include <cstdint>
#include <cstddef>

constexpr int N_NODES = 100000;
constexpr int N_EDGES = 20000;
constexpr int NNZ     = 1000000;
constexpr int NPAD    = 100096;  // 782 * 128

typedef __attribute__((ext_vector_type(8))) __bf16 bf16x8;
typedef __attribute__((ext_vector_type(4))) float f32x4;

// ---------------- bf16 split helpers (RNE) ----------------
__device__ __forceinline__ unsigned short bf16_rne(float v) {
  unsigned u = __builtin_bit_cast(unsigned, v);
  return (unsigned short)((u + 0x7FFFu + ((u >> 16) & 1u)) >> 16);
}
__device__ __forceinline__ void split2(float v, unsigned short& h, unsigned short& l) {
  unsigned u = __builtin_bit_cast(unsigned, v);
  unsigned hb = (u + 0x7FFFu + ((u >> 16) & 1u)) & 0xFFFF0000u;
  h = (unsigned short)(hb >> 16);
  float lo = v - __builtin_bit_cast(float, hb);
  l = bf16_rne(lo);
}
__device__ __forceinline__ float elu_f(float x) { return x > 0.f ? x : expm1f(x); }

// async global->LDS, 16B per lane; LDS dest is wave-uniform base (+lane*16 by HW)
__device__ __forceinline__ void gload_lds16(const void* g, void* l) {
  __builtin_amdgcn_global_load_lds(
      (const __attribute__((address_space(1))) unsigned int*)(uintptr_t)g,
      (__attribute__((address_space(3))) unsigned int*)(uintptr_t)l, 16, 0, 0);
}

// ---------------- degree counting ----------------
__global__ void count_kernel(const int* __restrict__ ni, const int* __restrict__ ei,
                             int* __restrict__ dcnt, int* __restrict__ bcnt) {
  int i = blockIdx.x * blockDim.x + threadIdx.x;
  if (i < NNZ) {
    atomicAdd(&dcnt[ni[i]], 1);
    atomicAdd(&bcnt[ei[i]], 1);
  }
}

__global__ void invert_kernel(const int* __restrict__ cnt, float* __restrict__ inv, int n) {
  int i = blockIdx.x * blockDim.x + threadIdx.x;
  if (i < n) {
    int c = cnt[i];
    inv[i] = c > 0 ? 1.0f / (float)c : 0.0f;
  }
}

// ---------------- exclusive scan (3-kernel) ----------------
template <int BS>
__global__ void scan_block(const int* __restrict__ cnt, int n, int* __restrict__ out,
                           int* __restrict__ partials) {
  __shared__ int buf[BS];
  int tid = threadIdx.x;
  int i = blockIdx.x * BS + tid;
  int v = (i < n) ? cnt[i] : 0;
  buf[tid] = v;
  __syncthreads();
  for (int o = 1; o < BS; o <<= 1) {
    int t = (tid >= o) ? buf[tid - o] : 0;
    __syncthreads();
    buf[tid] += t;
    __syncthreads();
  }
  if (i < n) out[i] = buf[tid] - v;
  if (tid == BS - 1) partials[blockIdx.x] = buf[tid];
}

__global__ void scan_partials(int* __restrict__ partials, int nb, int* __restrict__ total_out) {
  __shared__ int buf[1024];
  int tid = threadIdx.x;
  int v = (tid < nb) ? partials[tid] : 0;
  buf[tid] = v;
  __syncthreads();
  for (int o = 1; o < 1024; o <<= 1) {
    int t = (tid >= o) ? buf[tid - o] : 0;
    __syncthreads();
    buf[tid] += t;
    __syncthreads();
  }
  if (tid < nb) partials[tid] = buf[tid] - v;
  if (tid == 1023) *total_out = buf[1023];
}

__global__ void scan_add(int* __restrict__ out, int n, const int* __restrict__ partials) {
  int i = blockIdx.x * blockDim.x + threadIdx.x;
  if (i < n) out[i] += partials[blockIdx.x];
}

// ---------------- CSR fill (atomic cursors) ----------------
__global__ void fill_kernel(const int* __restrict__ ni, const int* __restrict__ ei,
                            const int* __restrict__ noff, const int* __restrict__ eoff,
                            int* __restrict__ ncur, int* __restrict__ ecur,
                            int* __restrict__ nedges, int* __restrict__ enodes) {
  int i = blockIdx.x * blockDim.x + threadIdx.x;
  if (i < NNZ) {
    int n = ni[i], e = ei[i];
    int p = atomicAdd(&ecur[e], 1);
    enodes[eoff[e] + p] = n;
    int q = atomicAdd(&ncur[n], 1);
    nedges[noff[n] + q] = e;
  }
}

// ---------------- W split+transpose: W[K][N] f32 -> Wt_h/Wt_l [NP][K] bf16 ----------------
__global__ void wsplit_t(const float* __restrict__ W, int K, int N, int NP,
                         unsigned short* __restrict__ Th, unsigned short* __restrict__ Tl) {
  int i = blockIdx.x * 256 + threadIdx.x;
  if (i >= NP * K) return;
  int n = i / K, k = i - n * K;
  float v = (n < N) ? W[(size_t)k * N + n] : 0.0f;
  unsigned short h, l;
  split2(v, h, l);
  Th[i] = h;
  Tl[i] = l;
}

// ---------------- LDS-staged split-bf16 MFMA GEMM ----------------
// C[M, N] = (Ah+Al)[M,K] @ (Bh+Bl)[K,N], 3-term split, f32 accum.
// LDS tiles: linear [row][64B]; 16B-slot XOR swizzle with the 2 in-row bits
// only: colbyte ^= ((row&3)<<4). Staged via global_load_lds with the inverse
// (same) permutation applied to the per-lane GLOBAL source address (rule 21);
// fragment ds_read_b128 applies the same XOR. Bijective within each 64-B row.
template <int MFR, int NFR, int WAVES_M, int WAVES_N, int EPI>
__global__ __launch_bounds__(256) void gemm_tile(
    const unsigned short* __restrict__ Ah, const unsigned short* __restrict__ Al,
    const unsigned short* __restrict__ Bh, const unsigned short* __restrict__ Bl,
    int K, const float* __restrict__ bias, float* __restrict__ outF,
    unsigned short* __restrict__ outH, unsigned short* __restrict__ outL, int ncols) {
  constexpr int BM = WAVES_M * MFR * 16;
  constexpr int BN = WAVES_N * NFR * 16;
  __shared__ char lds[(BM + BN) * 128];
  char* Ash = lds;
  char* Asl = lds + BM * 64;
  char* Bsh = lds + BM * 128;
  char* Bsl = lds + BM * 128 + BN * 64;

  const int wave = threadIdx.x >> 6;
  const int lane = threadIdx.x & 63;
  const int rl = lane & 15;
  const int g = lane >> 4;
  const int wr = wave / WAVES_N;
  const int wc = wave % WAVES_N;
  const int rowbase = blockIdx.x * BM;
  const int colbase = blockIdx.y * BN;

  f32x4 acc[MFR][NFR] = {};

  // stage one [R rows][32 K] bf16 tile: R*64 bytes, pre-swizzled source
  auto stage = [&](const unsigned short* G, char* S, int R, int rbase, int k0) {
    for (int wi = wave; wi < (R >> 4); wi += 4) {
      int c = wi * 64 + lane;
      int row = c >> 2;
      int colbyte = ((lane & 3) * 16) ^ ((row & 3) << 4);
      const char* src = (const char*)G + ((size_t)(rbase + row) * K + k0) * 2 + colbyte;
      gload_lds16(src, S + wi * 1024);
    }
  };

  for (int k0 = 0; k0 < K; k0 += 32) {
    stage(Ah, Ash, BM, rowbase, k0);
    stage(Al, Asl, BM, rowbase, k0);
    stage(Bh, Bsh, BN, colbase, k0);
    stage(Bl, Bsl, BN, colbase, k0);
    asm volatile("s_waitcnt vmcnt(0)" ::: "memory");
    __syncthreads();

    bf16x8 afh[MFR], afl[MFR], bfh[NFR], bfl[NFR];
#pragma unroll
    for (int mf = 0; mf < MFR; ++mf) {
      int r = wr * MFR * 16 + mf * 16 + rl;
      int addr = r * 64 + ((g * 16) ^ ((r & 3) << 4));
      afh[mf] = *(const bf16x8*)(Ash + addr);
      afl[mf] = *(const bf16x8*)(Asl + addr);
    }
#pragma unroll
    for (int nf = 0; nf < NFR; ++nf) {
      int r = wc * NFR * 16 + nf * 16 + rl;
      int addr = r * 64 + ((g * 16) ^ ((r & 3) << 4));
      bfh[nf] = *(const bf16x8*)(Bsh + addr);
      bfl[nf] = *(const bf16x8*)(Bsl + addr);
    }
#pragma unroll
    for (int mf = 0; mf < MFR; ++mf)
#pragma unroll
      for (int nf = 0; nf < NFR; ++nf) {
        acc[mf][nf] = __builtin_amdgcn_mfma_f32_16x16x32_bf16(afh[mf], bfh[nf], acc[mf][nf], 0, 0, 0);
        acc[mf][nf] = __builtin_amdgcn_mfma_f32_16x16x32_bf16(afh[mf], bfl[nf], acc[mf][nf], 0, 0, 0);
        acc[mf][nf] = __builtin_amdgcn_mfma_f32_16x16x32_bf16(afl[mf], bfh[nf], acc[mf][nf], 0, 0, 0);
      }
    __syncthreads();
  }

#pragma unroll
  for (int mf = 0; mf < MFR; ++mf)
#pragma unroll
    for (int nf = 0; nf < NFR; ++nf)
#pragma unroll
      for (int i = 0; i < 4; ++i) {
        int grow = rowbase + wr * MFR * 16 + mf * 16 + g * 4 + i;
        if (grow >= N_NODES) continue;
        int gcol = colbase + wc * NFR * 16 + nf * 16 + rl;
        float v = acc[mf][nf][i];
        if (EPI == 1) {
          v += bias[gcol];
          v = elu_f(v);
          unsigned short h, l;
          split2(v, h, l);
          size_t o = (size_t)grow * ncols + gcol;
          outH[o] = h;
          outL[o] = l;
        } else {
          if (gcol < ncols) outF[(size_t)grow * ncols + gcol] = v;
        }
      }
}

// ---------------- segment reductions ----------------
__global__ __launch_bounds__(256) void edge_reduce128(const float* __restrict__ x,
                                                      const int* __restrict__ eoff,
                                                      const int* __restrict__ enodes,
                                                      const float* __restrict__ binv,
                                                      float* __restrict__ m) {
  int w = (blockIdx.x * blockDim.x + threadIdx.x) >> 6;
  int lane = threadIdx.x & 63;
  if (w >= N_EDGES) return;
  int s = eoff[w], t = eoff[w + 1];
  float ax = 0.f, ay = 0.f;
  for (int j = s; j < t; ++j) {
    int nd = enodes[j];
    float2 v = *reinterpret_cast<const float2*>(&x[(size_t)nd * 128 + lane * 2]);
    ax += v.x;
    ay += v.y;
  }
  float bv = binv[w];
  float2 rr;
  rr.x = ax * bv;
  rr.y = ay * bv;
  *reinterpret_cast<float2*>(&m[(size_t)w * 128 + lane * 2]) = rr;
}

__global__ __launch_bounds__(256) void node_reduce128_split(const float* __restrict__ m,
                                                            const int* __restrict__ noff,
                                                            const int* __restrict__ nedges,
                                                            const float* __restrict__ dinv,
                                                            unsigned short* __restrict__ Ah,
                                                            unsigned short* __restrict__ Al) {
  int w = (blockIdx.x * blockDim.x + threadIdx.x) >> 6;
  int lane = threadIdx.x & 63;
  if (w >= N_NODES) return;
  int s = noff[w], t = noff[w + 1];
  float ax = 0.f, ay = 0.f;
  for (int j = s; j < t; ++j) {
    int ed = nedges[j];
    float2 v = *reinterpret_cast<const float2*>(&m[(size_t)ed * 128 + lane * 2]);
    ax += v.x;
    ay += v.y;
  }
  float dv = dinv[w];
  ax *= dv;
  ay *= dv;
  unsigned short h0, l0, h1, l1;
  split2(ax, h0, l0);
  split2(ay, h1, l1);
  unsigned ph = (unsigned)h0 | ((unsigned)h1 << 16);
  unsigned pl = (unsigned)l0 | ((unsigned)l1 << 16);
  *reinterpret_cast<unsigned*>(&Ah[(size_t)w * 128 + lane * 2]) = ph;
  *reinterpret_cast<unsigned*>(&Al[(size_t)w * 128 + lane * 2]) = pl;
}

__global__ __launch_bounds__(256) void edge_reduce256(const float* __restrict__ xw,
                                                      const int* __restrict__ eoff,
                                                      const int* __restrict__ enodes,
                                                      const float* __restrict__ binv,
                                                      float* __restrict__ m) {
  int w = (blockIdx.x * blockDim.x + threadIdx.x) >> 6;
  int lane = threadIdx.x & 63;
  if (w >= N_EDGES) return;
  int s = eoff[w], t = eoff[w + 1];
  float ax = 0.f, ay = 0.f, az = 0.f, aw = 0.f;
  for (int j = s; j < t; ++j) {
    int nd = enodes[j];
    float4 v = *reinterpret_cast<const float4*>(&xw[(size_t)nd * 256 + lane * 4]);
    ax += v.x;
    ay += v.y;
    az += v.z;
    aw += v.w;
  }
  float bv = binv[w];
  float4 rr;
  rr.x = ax * bv;
  rr.y = ay * bv;
  rr.z = az * bv;
  rr.w = aw * bv;
  *reinterpret_cast<float4*>(&m[(size_t)w * 256 + lane * 4]) = rr;
}

__global__ __launch_bounds__(256) void node_reduce256_split_elu(
    const float* __restrict__ m, const int* __restrict__ noff,
    const int* __restrict__ nedges, const float* __restrict__ dinv,
    const float* __restrict__ bias, unsigned short* __restrict__ Ah,
    unsigned short* __restrict__ Al) {
  int w = (blockIdx.x * blockDim.x + threadIdx.x) >> 6;
  int lane = threadIdx.x & 63;
  if (w >= N_NODES) return;
  int s = noff[w], t = noff[w + 1];
  float ax = 0.f, ay = 0.f, az = 0.f, aw = 0.f;
  for (int j = s; j < t; ++j) {
    int ed = nedges[j];
    float4 v = *reinterpret_cast<const float4*>(&m[(size_t)ed * 256 + lane * 4]);
    ax += v.x;
    ay += v.y;
    az += v.z;
    aw += v.w;
  }
  float dv = dinv[w];
  float4 b4 = *reinterpret_cast<const float4*>(&bias[lane * 4]);
  float v0 = elu_f(ax * dv + b4.x);
  float v1 = elu_f(ay * dv + b4.y);
  float v2 = elu_f(az * dv + b4.z);
  float v3 = elu_f(aw * dv + b4.w);
  unsigned short h0, l0, h1, l1, h2, l2, h3, l3;
  split2(v0, h0, l0);
  split2(v1, h1, l1);
  split2(v2, h2, l2);
  split2(v3, h3, l3);
  uint2 ph, pl;
  ph.x = (unsigned)h0 | ((unsigned)h1 << 16);
  ph.y = (unsigned)h2 | ((unsigned)h3 << 16);
  pl.x = (unsigned)l0 | ((unsigned)l1 << 16);
  pl.y = (unsigned)l2 | ((unsigned)l3 << 16);
  *reinterpret_cast<uint2*>(&Ah[(size_t)w * 256 + lane * 4]) = ph;
  *reinterpret_cast<uint2*>(&Al[(size_t)w * 256 + lane * 4]) = pl;
}

__global__ __launch_bounds__(256) void edge_reduce40(const float* __restrict__ xw,
                                                     const int* __restrict__ eoff,
                                                     const int* __restrict__ enodes,
                                                     const float* __restrict__ binv,
                                                     float* __restrict__ m) {
  int w = (blockIdx.x * blockDim.x + threadIdx.x) >> 6;
  int lane = threadIdx.x & 63;
  if (w >= N_EDGES || lane >= 40) return;
  int s = eoff[w], t = eoff[w + 1];
  float acc = 0.f;
  for (int j = s; j < t; ++j) {
    int nd = enodes[j];
    acc += xw[(size_t)nd * 40 + lane];
  }
  m[(size_t)w * 40 + lane] = acc * binv[w];
}

__global__ __launch_bounds__(256) void node_reduce40(const float* __restrict__ m,
                                                     const int* __restrict__ noff,
                                                     const int* __restrict__ nedges,
                                                     const float* __restrict__ dinv,
                                                     const float* __restrict__ bias,
                                                     float* __restrict__ out) {
  int w = (blockIdx.x * blockDim.x + threadIdx.x) >> 6;
  int lane = threadIdx.x & 63;
  if (w >= N_NODES || lane >= 40) return;
  int s = noff[w], t = noff[w + 1];
  float acc = 0.f;
  for (int j = s; j < t; ++j) {
    int ed = nedges[j];
    acc += m[(size_t)ed * 40 + lane];
  }
  out[(size_t)w * 40 + lane] = acc * dinv[w] + bias[lane];
}

// ---------------- launch ----------------
extern "C" void kernel_launch(void* const* d_in, const int* in_sizes, int n_in,
                              void* d_out, int out_size, void* d_ws, size_t ws_size,
                              hipStream_t stream) {
  const float* x  = (const float*)d_in[0];
  const int*   ni = (const int*)d_in[1];
  const int*   ei = (const int*)d_in[2];
  const float* W1 = (const float*)d_in[3];
  const float* b1 = (const float*)d_in[4];
  const float* W2 = (const float*)d_in[5];
  const float* b2 = (const float*)d_in[6];
  const float* W3 = (const float*)d_in[7];
  const float* b3 = (const float*)d_in[8];
  float* out = (float*)d_out;

  char* base = (char*)d_ws;
  size_t off = 0;
  auto take = [&](size_t bytes) -> char* {
    char* p = base + off;
    off += (bytes + 255) & ~(size_t)255;
    return p;
  };

  // CSR region (live for entire call)
  int* dcnt   = (int*)take((size_t)N_NODES * 4);
  int* bcnt   = (int*)take((size_t)N_EDGES * 4);
  int* ncur   = (int*)take((size_t)N_NODES * 4);
  int* ecur   = (int*)take((size_t)N_EDGES * 4);
  int* noff   = (int*)take((size_t)(N_NODES + 1) * 4);
  int* eoff   = (int*)take((size_t)(N_EDGES + 1) * 4);
  int* npart  = (int*)take((size_t)((N_NODES + 255) / 256) * 4);
  int* epart  = (int*)take((size_t)((N_EDGES + 255) / 256) * 4);
  int* nedges = (int*)take((size_t)NNZ * 4);
  int* enodes = (int*)take((size_t)NNZ * 4);
  float* dinv = (float*)take((size_t)N_NODES * 4);
  float* binv = (float*)take((size_t)N_EDGES * 4);

  // W splits (live entire call)
  unsigned short* W1th = (unsigned short*)take((size_t)256 * 128 * 2);
  unsigned short* W1tl = (unsigned short*)take((size_t)256 * 128 * 2);
  unsigned short* W2th = (unsigned short*)take((size_t)256 * 256 * 2);
  unsigned short* W2tl = (unsigned short*)take((size_t)256 * 256 * 2);
  unsigned short* W3th = (unsigned short*)take((size_t)48 * 256 * 2);
  unsigned short* W3tl = (unsigned short*)take((size_t)48 * 256 * 2);

  // Big regions with liveness-based aliasing
  const size_t A2B = (size_t)NPAD * 256 * 2;  // one bf16 [NPAD][256]
  const size_t A1B = (size_t)NPAD * 128 * 2;
  char* R2 = take(2 * A2B);
  char* R3 = take(2 * A2B);

  // R2: [A2h | A2l] (gemm1 out, gemm2 in) -> then m256 in A2l slot, t3+m40 in A2h slot
  unsigned short* A2h = (unsigned short*)R2;
  unsigned short* A2l = (unsigned short*)(R2 + A2B);
  float* m256 = (float*)(R2 + A2B);
  float* t3   = (float*)R2;
  float* m40  = (float*)(R2 + 16015360);

  // R3: [m128 | A1h | A1l] early -> t2 (gemm2 out) -> [A3h | A3l]
  float* m128 = (float*)R3;
  unsigned short* A1h = (unsigned short*)(R3 + 10240000);
  unsigned short* A1l = (unsigned short*)(R3 + 10240000 + A1B);
  float* t2 = (float*)R3;
  unsigned short* A3h = (unsigned short*)R3;
  unsigned short* A3l = (unsigned short*)(R3 + A2B);

  // ---- CSR build ----
  hipMemsetAsync(dcnt, 0, (size_t)N_NODES * 4, stream);
  hipMemsetAsync(bcnt, 0, (size_t)N_EDGES * 4, stream);
  hipMemsetAsync(ncur, 0, (size_t)N_NODES * 4, stream);
  hipMemsetAsync(ecur, 0, (size_t)N_EDGES * 4, stream);

  count_kernel<<<(NNZ + 255) / 256, 256, 0, stream>>>(ni, ei, dcnt, bcnt);
  invert_kernel<<<(N_NODES + 255) / 256, 256, 0, stream>>>(dcnt, dinv, N_NODES);
  invert_kernel<<<(N_EDGES + 255) / 256, 256, 0, stream>>>(bcnt, binv, N_EDGES);

  const int nb_n = (N_NODES + 255) / 256;
  const int nb_e = (N_EDGES + 255) / 256;
  scan_block<256><<<nb_n, 256, 0, stream>>>(dcnt, N_NODES, noff, npart);
  scan_block<256><<<nb_e, 256, 0, stream>>>(bcnt, N_EDGES, eoff, epart);
  scan_partials<<<1, 1024, 0, stream>>>(npart, nb_n, &noff[N_NODES]);
  scan_partials<<<1, 1024, 0, stream>>>(epart, nb_e, &eoff[N_EDGES]);
  scan_add<<<nb_n, 256, 0, stream>>>(noff, N_NODES, npart);
  scan_add<<<nb_e, 256, 0, stream>>>(eoff, N_EDGES, epart);

  fill_kernel<<<(NNZ + 255) / 256, 256, 0, stream>>>(ni, ei, noff, eoff, ncur, ecur, nedges, enodes);

  // ---- W pre-split (transposed) ----
  wsplit_t<<<(256 * 128 + 255) / 256, 256, 0, stream>>>(W1, 128, 256, 256, W1th, W1tl);
  wsplit_t<<<(256 * 256 + 255) / 256, 256, 0, stream>>>(W2, 256, 256, 256, W2th, W2tl);
  wsplit_t<<<(48 * 256 + 255) / 256, 256, 0, stream>>>(W3, 256, 40, 48, W3th, W3tl);

  const int eblocks = (N_EDGES * 64 + 255) / 256;  // 5000
  const int nblocks = (N_NODES * 64 + 255) / 256;  // 25000
  const int gm = NPAD / 128;                       // 782

  // ---- Layer 1: agg = Dinv H Binv H^T x  (F=128), then h1 = elu(agg@W1 + b1) ----
  edge_reduce128<<<eblocks, 256, 0, stream>>>(x, eoff, enodes, binv, m128);
  node_reduce128_split<<<nblocks, 256, 0, stream>>>(m128, noff, nedges, dinv, A1h, A1l);
  gemm_tile<4, 4, 2, 2, 1><<<dim3(gm, 2), 256, 0, stream>>>(
      A1h, A1l, W1th, W1tl, 128, b1, nullptr, A2h, A2l, 256);

  // ---- Layer 2: t2 = h1@W2 ; h2 = elu(Dinv H Binv H^T t2 + b2) ----
  gemm_tile<4, 4, 2, 2, 0><<<dim3(gm, 2), 256, 0, stream>>>(
      A2h, A2l, W2th, W2tl, 256, nullptr, t2, nullptr, nullptr, 256);
  edge_reduce256<<<eblocks, 256, 0, stream>>>(t2, eoff, enodes, binv, m256);
  node_reduce256_split_elu<<<nblocks, 256, 0, stream>>>(m256, noff, nedges, dinv, b2, A3h, A3l);

  // ---- Layer 3: t3 = h2@W3 ; out = Dinv H Binv H^T t3 + b3 ----
  gemm_tile<2, 3, 4, 1, 0><<<dim3(gm, 1), 256, 0, stream>>>(
      A3h, A3l, W3th, W3tl, 256, nullptr, t3, nullptr, nullptr, 40);
  edge_reduce40<<<eblocks, 256, 0, stream>>>(t3, eoff, enodes, binv, m40);
  node_reduce40<<<nblocks, 256, 0, stream>>>(m40, noff, nedges, dinv, b3, out);
}

// Round 5
// 888.984 us; speedup vs baseline: 1.5371x; 1.2004x over previous
//
#include <hip/hip_runtime.h>
#include <cstdint>
#include <cstddef>

constexpr int N_NODES = 100000;
constexpr int N_EDGES = 20000;
constexpr int NNZ     = 1000000;
constexpr int NPAD    = 100096;  // 782 * 128

typedef __attribute__((ext_vector_type(8))) __bf16 bf16x8;
typedef __attribute__((ext_vector_type(4))) float f32x4;

// ---------------- bf16 split helpers (RNE) ----------------
__device__ __forceinline__ unsigned short bf16_rne(float v) {
  unsigned u = __builtin_bit_cast(unsigned, v);
  return (unsigned short)((u + 0x7FFFu + ((u >> 16) & 1u)) >> 16);
}
__device__ __forceinline__ void split2(float v, unsigned short& h, unsigned short& l) {
  unsigned u = __builtin_bit_cast(unsigned, v);
  unsigned hb = (u + 0x7FFFu + ((u >> 16) & 1u)) & 0xFFFF0000u;
  h = (unsigned short)(hb >> 16);
  float lo = v - __builtin_bit_cast(float, hb);
  l = bf16_rne(lo);
}
__device__ __forceinline__ float elu_f(float x) { return x > 0.f ? x : expm1f(x); }

// async global->LDS, 16B per lane; LDS dest is wave-uniform base (+lane*16 by HW)
__device__ __forceinline__ void gload_lds16(const void* g, void* l) {
  __builtin_amdgcn_global_load_lds(
      (const __attribute__((address_space(1))) unsigned int*)(uintptr_t)g,
      (__attribute__((address_space(3))) unsigned int*)(uintptr_t)l, 16, 0, 0);
}

// ---------------- degree counting ----------------
__global__ void count_kernel(const int* __restrict__ ni, const int* __restrict__ ei,
                             int* __restrict__ dcnt, int* __restrict__ bcnt) {
  int i = blockIdx.x * blockDim.x + threadIdx.x;
  if (i < NNZ) {
    atomicAdd(&dcnt[ni[i]], 1);
    atomicAdd(&bcnt[ei[i]], 1);
  }
}

__global__ void invert_kernel(const int* __restrict__ cnt, float* __restrict__ inv, int n) {
  int i = blockIdx.x * blockDim.x + threadIdx.x;
  if (i < n) {
    int c = cnt[i];
    inv[i] = c > 0 ? 1.0f / (float)c : 0.0f;
  }
}

// ---------------- exclusive scan (3-kernel) ----------------
template <int BS>
__global__ void scan_block(const int* __restrict__ cnt, int n, int* __restrict__ out,
                           int* __restrict__ partials) {
  __shared__ int buf[BS];
  int tid = threadIdx.x;
  int i = blockIdx.x * BS + tid;
  int v = (i < n) ? cnt[i] : 0;
  buf[tid] = v;
  __syncthreads();
  for (int o = 1; o < BS; o <<= 1) {
    int t = (tid >= o) ? buf[tid - o] : 0;
    __syncthreads();
    buf[tid] += t;
    __syncthreads();
  }
  if (i < n) out[i] = buf[tid] - v;
  if (tid == BS - 1) partials[blockIdx.x] = buf[tid];
}

__global__ void scan_partials(int* __restrict__ partials, int nb, int* __restrict__ total_out) {
  __shared__ int buf[1024];
  int tid = threadIdx.x;
  int v = (tid < nb) ? partials[tid] : 0;
  buf[tid] = v;
  __syncthreads();
  for (int o = 1; o < 1024; o <<= 1) {
    int t = (tid >= o) ? buf[tid - o] : 0;
    __syncthreads();
    buf[tid] += t;
    __syncthreads();
  }
  if (tid < nb) partials[tid] = buf[tid] - v;
  if (tid == 1023) *total_out = buf[1023];
}

__global__ void scan_add(int* __restrict__ out, int n, const int* __restrict__ partials) {
  int i = blockIdx.x * blockDim.x + threadIdx.x;
  if (i < n) out[i] += partials[blockIdx.x];
}

// ---------------- CSR fill (atomic cursors) ----------------
__global__ void fill_kernel(const int* __restrict__ ni, const int* __restrict__ ei,
                            const int* __restrict__ noff, const int* __restrict__ eoff,
                            int* __restrict__ ncur, int* __restrict__ ecur,
                            int* __restrict__ nedges, int* __restrict__ enodes) {
  int i = blockIdx.x * blockDim.x + threadIdx.x;
  if (i < NNZ) {
    int n = ni[i], e = ei[i];
    int p = atomicAdd(&ecur[e], 1);
    enodes[eoff[e] + p] = n;
    int q = atomicAdd(&ncur[n], 1);
    nedges[noff[n] + q] = e;
  }
}

// ---------------- W split+transpose: W[K][N] f32 -> Wt_h/Wt_l [NP][K] bf16 ----------------
__global__ void wsplit_t(const float* __restrict__ W, int K, int N, int NP,
                         unsigned short* __restrict__ Th, unsigned short* __restrict__ Tl) {
  int i = blockIdx.x * 256 + threadIdx.x;
  if (i >= NP * K) return;
  int n = i / K, k = i - n * K;
  float v = (n < N) ? W[(size_t)k * N + n] : 0.0f;
  unsigned short h, l;
  split2(v, h, l);
  Th[i] = h;
  Tl[i] = l;
}

// ---------------- LDS-staged split-bf16 MFMA GEMM ----------------
// C[M, N] = (Ah+Al)[M,K] @ (Bh+Bl)[K,N], 3-term split, f32 accum.
// LDS tiles: linear [row][64B]; 16B-slot XOR swizzle with the 2 in-row bits
// only: colbyte ^= ((row&3)<<4). Staged via global_load_lds with the same
// permutation applied to the per-lane GLOBAL source address (rule 21);
// fragment ds_read_b128 applies the same XOR. Bijective within each 64-B row.
template <int MFR, int NFR, int WAVES_M, int WAVES_N, int EPI>
__global__ __launch_bounds__(256) void gemm_tile(
    const unsigned short* __restrict__ Ah, const unsigned short* __restrict__ Al,
    const unsigned short* __restrict__ Bh, const unsigned short* __restrict__ Bl,
    int K, const float* __restrict__ bias, float* __restrict__ outF,
    unsigned short* __restrict__ outH, unsigned short* __restrict__ outL, int ncols) {
  constexpr int BM = WAVES_M * MFR * 16;
  constexpr int BN = WAVES_N * NFR * 16;
  __shared__ char lds[(BM + BN) * 128];
  char* Ash = lds;
  char* Asl = lds + BM * 64;
  char* Bsh = lds + BM * 128;
  char* Bsl = lds + BM * 128 + BN * 64;

  const int wave = threadIdx.x >> 6;
  const int lane = threadIdx.x & 63;
  const int rl = lane & 15;
  const int g = lane >> 4;
  const int wr = wave / WAVES_N;
  const int wc = wave % WAVES_N;
  const int rowbase = blockIdx.x * BM;
  const int colbase = blockIdx.y * BN;

  f32x4 acc[MFR][NFR] = {};

  // stage one [R rows][32 K] bf16 tile: R*64 bytes, pre-swizzled source
  auto stage = [&](const unsigned short* G, char* S, int R, int rbase, int k0) {
    for (int wi = wave; wi < (R >> 4); wi += 4) {
      int c = wi * 64 + lane;
      int row = c >> 2;
      int colbyte = ((lane & 3) * 16) ^ ((row & 3) << 4);
      const char* src = (const char*)G + ((size_t)(rbase + row) * K + k0) * 2 + colbyte;
      gload_lds16(src, S + wi * 1024);
    }
  };

  for (int k0 = 0; k0 < K; k0 += 32) {
    stage(Ah, Ash, BM, rowbase, k0);
    stage(Al, Asl, BM, rowbase, k0);
    stage(Bh, Bsh, BN, colbase, k0);
    stage(Bl, Bsl, BN, colbase, k0);
    asm volatile("s_waitcnt vmcnt(0)" ::: "memory");
    __syncthreads();

    bf16x8 afh[MFR], afl[MFR], bfh[NFR], bfl[NFR];
#pragma unroll
    for (int mf = 0; mf < MFR; ++mf) {
      int r = wr * MFR * 16 + mf * 16 + rl;
      int addr = r * 64 + ((g * 16) ^ ((r & 3) << 4));
      afh[mf] = *(const bf16x8*)(Ash + addr);
      afl[mf] = *(const bf16x8*)(Asl + addr);
    }
#pragma unroll
    for (int nf = 0; nf < NFR; ++nf) {
      int r = wc * NFR * 16 + nf * 16 + rl;
      int addr = r * 64 + ((g * 16) ^ ((r & 3) << 4));
      bfh[nf] = *(const bf16x8*)(Bsh + addr);
      bfl[nf] = *(const bf16x8*)(Bsl + addr);
    }
#pragma unroll
    for (int mf = 0; mf < MFR; ++mf)
#pragma unroll
      for (int nf = 0; nf < NFR; ++nf) {
        acc[mf][nf] = __builtin_amdgcn_mfma_f32_16x16x32_bf16(afh[mf], bfh[nf], acc[mf][nf], 0, 0, 0);
        acc[mf][nf] = __builtin_amdgcn_mfma_f32_16x16x32_bf16(afh[mf], bfl[nf], acc[mf][nf], 0, 0, 0);
        acc[mf][nf] = __builtin_amdgcn_mfma_f32_16x16x32_bf16(afl[mf], bfh[nf], acc[mf][nf], 0, 0, 0);
      }
    __syncthreads();
  }

#pragma unroll
  for (int mf = 0; mf < MFR; ++mf)
#pragma unroll
    for (int nf = 0; nf < NFR; ++nf)
#pragma unroll
      for (int i = 0; i < 4; ++i) {
        int grow = rowbase + wr * MFR * 16 + mf * 16 + g * 4 + i;
        if (grow >= N_NODES) continue;
        int gcol = colbase + wc * NFR * 16 + nf * 16 + rl;
        float v = acc[mf][nf][i];
        if (EPI == 1) {
          v += bias[gcol];
          v = elu_f(v);
          unsigned short h, l;
          split2(v, h, l);
          size_t o = (size_t)grow * ncols + gcol;
          outH[o] = h;
          outL[o] = l;
        } else {
          if (gcol < ncols) outF[(size_t)grow * ncols + gcol] = v;
        }
      }
}

// ---------------- segment reductions (4x unrolled, 4 independent accumulators) ----------------
#define ACC4(a, v) { a.x += v.x; a.y += v.y; a.z += v.z; a.w += v.w; }

__global__ __launch_bounds__(256) void edge_reduce256(const float* __restrict__ xw,
                                                      const int* __restrict__ eoff,
                                                      const int* __restrict__ enodes,
                                                      const float* __restrict__ binv,
                                                      float* __restrict__ m) {
  int w = (blockIdx.x * blockDim.x + threadIdx.x) >> 6;
  int lane = threadIdx.x & 63;
  if (w >= N_EDGES) return;
  int s = eoff[w], t = eoff[w + 1];
  float4 a0 = {0, 0, 0, 0}, a1 = {0, 0, 0, 0}, a2 = {0, 0, 0, 0}, a3 = {0, 0, 0, 0};
  int j = s;
  for (; j < t && (j & 3); ++j) {
    float4 v = *reinterpret_cast<const float4*>(&xw[(size_t)enodes[j] * 256 + lane * 4]);
    ACC4(a0, v);
  }
  for (; j + 4 <= t; j += 4) {
    int4 idx = *reinterpret_cast<const int4*>(enodes + j);
    float4 v0 = *reinterpret_cast<const float4*>(&xw[(size_t)idx.x * 256 + lane * 4]);
    float4 v1 = *reinterpret_cast<const float4*>(&xw[(size_t)idx.y * 256 + lane * 4]);
    float4 v2 = *reinterpret_cast<const float4*>(&xw[(size_t)idx.z * 256 + lane * 4]);
    float4 v3 = *reinterpret_cast<const float4*>(&xw[(size_t)idx.w * 256 + lane * 4]);
    ACC4(a0, v0); ACC4(a1, v1); ACC4(a2, v2); ACC4(a3, v3);
  }
  for (; j < t; ++j) {
    float4 v = *reinterpret_cast<const float4*>(&xw[(size_t)enodes[j] * 256 + lane * 4]);
    ACC4(a0, v);
  }
  float bv = binv[w];
  float4 r;
  r.x = (a0.x + a1.x + a2.x + a3.x) * bv;
  r.y = (a0.y + a1.y + a2.y + a3.y) * bv;
  r.z = (a0.z + a1.z + a2.z + a3.z) * bv;
  r.w = (a0.w + a1.w + a2.w + a3.w) * bv;
  *reinterpret_cast<float4*>(&m[(size_t)w * 256 + lane * 4]) = r;
}

__global__ __launch_bounds__(256) void node_reduce256_split_elu(
    const float* __restrict__ m, const int* __restrict__ noff,
    const int* __restrict__ nedges, const float* __restrict__ dinv,
    const float* __restrict__ bias, unsigned short* __restrict__ Ah,
    unsigned short* __restrict__ Al) {
  int w = (blockIdx.x * blockDim.x + threadIdx.x) >> 6;
  int lane = threadIdx.x & 63;
  if (w >= N_NODES) return;
  int s = noff[w], t = noff[w + 1];
  float4 a0 = {0, 0, 0, 0}, a1 = {0, 0, 0, 0}, a2 = {0, 0, 0, 0}, a3 = {0, 0, 0, 0};
  int j = s;
  for (; j < t && (j & 3); ++j) {
    float4 v = *reinterpret_cast<const float4*>(&m[(size_t)nedges[j] * 256 + lane * 4]);
    ACC4(a0, v);
  }
  for (; j + 4 <= t; j += 4) {
    int4 idx = *reinterpret_cast<const int4*>(nedges + j);
    float4 v0 = *reinterpret_cast<const float4*>(&m[(size_t)idx.x * 256 + lane * 4]);
    float4 v1 = *reinterpret_cast<const float4*>(&m[(size_t)idx.y * 256 + lane * 4]);
    float4 v2 = *reinterpret_cast<const float4*>(&m[(size_t)idx.z * 256 + lane * 4]);
    float4 v3 = *reinterpret_cast<const float4*>(&m[(size_t)idx.w * 256 + lane * 4]);
    ACC4(a0, v0); ACC4(a1, v1); ACC4(a2, v2); ACC4(a3, v3);
  }
  for (; j < t; ++j) {
    float4 v = *reinterpret_cast<const float4*>(&m[(size_t)nedges[j] * 256 + lane * 4]);
    ACC4(a0, v);
  }
  float dv = dinv[w];
  float4 b4 = *reinterpret_cast<const float4*>(&bias[lane * 4]);
  float v0 = elu_f((a0.x + a1.x + a2.x + a3.x) * dv + b4.x);
  float v1 = elu_f((a0.y + a1.y + a2.y + a3.y) * dv + b4.y);
  float v2 = elu_f((a0.z + a1.z + a2.z + a3.z) * dv + b4.z);
  float v3 = elu_f((a0.w + a1.w + a2.w + a3.w) * dv + b4.w);
  unsigned short h0, l0, h1, l1, h2, l2, h3, l3;
  split2(v0, h0, l0);
  split2(v1, h1, l1);
  split2(v2, h2, l2);
  split2(v3, h3, l3);
  uint2 ph, pl;
  ph.x = (unsigned)h0 | ((unsigned)h1 << 16);
  ph.y = (unsigned)h2 | ((unsigned)h3 << 16);
  pl.x = (unsigned)l0 | ((unsigned)l1 << 16);
  pl.y = (unsigned)l2 | ((unsigned)l3 << 16);
  *reinterpret_cast<uint2*>(&Ah[(size_t)w * 256 + lane * 4]) = ph;
  *reinterpret_cast<uint2*>(&Al[(size_t)w * 256 + lane * 4]) = pl;
}

__global__ __launch_bounds__(256) void edge_reduce128(const float* __restrict__ x,
                                                      const int* __restrict__ eoff,
                                                      const int* __restrict__ enodes,
                                                      const float* __restrict__ binv,
                                                      float* __restrict__ m) {
  int w = (blockIdx.x * blockDim.x + threadIdx.x) >> 6;
  int lane = threadIdx.x & 63;
  if (w >= N_EDGES) return;
  int s = eoff[w], t = eoff[w + 1];
  float2 a0 = {0, 0}, a1 = {0, 0}, a2 = {0, 0}, a3 = {0, 0};
  int j = s;
  for (; j < t && (j & 3); ++j) {
    float2 v = *reinterpret_cast<const float2*>(&x[(size_t)enodes[j] * 128 + lane * 2]);
    a0.x += v.x; a0.y += v.y;
  }
  for (; j + 4 <= t; j += 4) {
    int4 idx = *reinterpret_cast<const int4*>(enodes + j);
    float2 v0 = *reinterpret_cast<const float2*>(&x[(size_t)idx.x * 128 + lane * 2]);
    float2 v1 = *reinterpret_cast<const float2*>(&x[(size_t)idx.y * 128 + lane * 2]);
    float2 v2 = *reinterpret_cast<const float2*>(&x[(size_t)idx.z * 128 + lane * 2]);
    float2 v3 = *reinterpret_cast<const float2*>(&x[(size_t)idx.w * 128 + lane * 2]);
    a0.x += v0.x; a0.y += v0.y;
    a1.x += v1.x; a1.y += v1.y;
    a2.x += v2.x; a2.y += v2.y;
    a3.x += v3.x; a3.y += v3.y;
  }
  for (; j < t; ++j) {
    float2 v = *reinterpret_cast<const float2*>(&x[(size_t)enodes[j] * 128 + lane * 2]);
    a0.x += v.x; a0.y += v.y;
  }
  float bv = binv[w];
  float2 r;
  r.x = (a0.x + a1.x + a2.x + a3.x) * bv;
  r.y = (a0.y + a1.y + a2.y + a3.y) * bv;
  *reinterpret_cast<float2*>(&m[(size_t)w * 128 + lane * 2]) = r;
}

__global__ __launch_bounds__(256) void node_reduce128_split(const float* __restrict__ m,
                                                            const int* __restrict__ noff,
                                                            const int* __restrict__ nedges,
                                                            const float* __restrict__ dinv,
                                                            unsigned short* __restrict__ Ah,
                                                            unsigned short* __restrict__ Al) {
  int w = (blockIdx.x * blockDim.x + threadIdx.x) >> 6;
  int lane = threadIdx.x & 63;
  if (w >= N_NODES) return;
  int s = noff[w], t = noff[w + 1];
  float2 a0 = {0, 0}, a1 = {0, 0}, a2 = {0, 0}, a3 = {0, 0};
  int j = s;
  for (; j < t && (j & 3); ++j) {
    float2 v = *reinterpret_cast<const float2*>(&m[(size_t)nedges[j] * 128 + lane * 2]);
    a0.x += v.x; a0.y += v.y;
  }
  for (; j + 4 <= t; j += 4) {
    int4 idx = *reinterpret_cast<const int4*>(nedges + j);
    float2 v0 = *reinterpret_cast<const float2*>(&m[(size_t)idx.x * 128 + lane * 2]);
    float2 v1 = *reinterpret_cast<const float2*>(&m[(size_t)idx.y * 128 + lane * 2]);
    float2 v2 = *reinterpret_cast<const float2*>(&m[(size_t)idx.z * 128 + lane * 2]);
    float2 v3 = *reinterpret_cast<const float2*>(&m[(size_t)idx.w * 128 + lane * 2]);
    a0.x += v0.x; a0.y += v0.y;
    a1.x += v1.x; a1.y += v1.y;
    a2.x += v2.x; a2.y += v2.y;
    a3.x += v3.x; a3.y += v3.y;
  }
  for (; j < t; ++j) {
    float2 v = *reinterpret_cast<const float2*>(&m[(size_t)nedges[j] * 128 + lane * 2]);
    a0.x += v.x; a0.y += v.y;
  }
  float dv = dinv[w];
  float ax = (a0.x + a1.x + a2.x + a3.x) * dv;
  float ay = (a0.y + a1.y + a2.y + a3.y) * dv;
  unsigned short h0, l0, h1, l1;
  split2(ax, h0, l0);
  split2(ay, h1, l1);
  unsigned ph = (unsigned)h0 | ((unsigned)h1 << 16);
  unsigned pl = (unsigned)l0 | ((unsigned)l1 << 16);
  *reinterpret_cast<unsigned*>(&Ah[(size_t)w * 128 + lane * 2]) = ph;
  *reinterpret_cast<unsigned*>(&Al[(size_t)w * 128 + lane * 2]) = pl;
}

__global__ __launch_bounds__(256) void edge_reduce40(const float* __restrict__ xw,
                                                     const int* __restrict__ eoff,
                                                     const int* __restrict__ enodes,
                                                     const float* __restrict__ binv,
                                                     float* __restrict__ m) {
  int w = (blockIdx.x * blockDim.x + threadIdx.x) >> 6;
  int lane = threadIdx.x & 63;
  if (w >= N_EDGES || lane >= 40) return;
  int s = eoff[w], t = eoff[w + 1];
  float a0 = 0.f, a1 = 0.f, a2 = 0.f, a3 = 0.f;
  int j = s;
  for (; j < t && (j & 3); ++j) a0 += xw[(size_t)enodes[j] * 40 + lane];
  for (; j + 4 <= t; j += 4) {
    int4 idx = *reinterpret_cast<const int4*>(enodes + j);
    a0 += xw[(size_t)idx.x * 40 + lane];
    a1 += xw[(size_t)idx.y * 40 + lane];
    a2 += xw[(size_t)idx.z * 40 + lane];
    a3 += xw[(size_t)idx.w * 40 + lane];
  }
  for (; j < t; ++j) a0 += xw[(size_t)enodes[j] * 40 + lane];
  m[(size_t)w * 40 + lane] = (a0 + a1 + a2 + a3) * binv[w];
}

__global__ __launch_bounds__(256) void node_reduce40(const float* __restrict__ m,
                                                     const int* __restrict__ noff,
                                                     const int* __restrict__ nedges,
                                                     const float* __restrict__ dinv,
                                                     const float* __restrict__ bias,
                                                     float* __restrict__ out) {
  int w = (blockIdx.x * blockDim.x + threadIdx.x) >> 6;
  int lane = threadIdx.x & 63;
  if (w >= N_NODES || lane >= 40) return;
  int s = noff[w], t = noff[w + 1];
  float a0 = 0.f, a1 = 0.f, a2 = 0.f, a3 = 0.f;
  int j = s;
  for (; j < t && (j & 3); ++j) a0 += m[(size_t)nedges[j] * 40 + lane];
  for (; j + 4 <= t; j += 4) {
    int4 idx = *reinterpret_cast<const int4*>(nedges + j);
    a0 += m[(size_t)idx.x * 40 + lane];
    a1 += m[(size_t)idx.y * 40 + lane];
    a2 += m[(size_t)idx.z * 40 + lane];
    a3 += m[(size_t)idx.w * 40 + lane];
  }
  for (; j < t; ++j) a0 += m[(size_t)nedges[j] * 40 + lane];
  out[(size_t)w * 40 + lane] = (a0 + a1 + a2 + a3) * dinv[w] + bias[lane];
}

// ---------------- launch ----------------
extern "C" void kernel_launch(void* const* d_in, const int* in_sizes, int n_in,
                              void* d_out, int out_size, void* d_ws, size_t ws_size,
                              hipStream_t stream) {
  const float* x  = (const float*)d_in[0];
  const int*   ni = (const int*)d_in[1];
  const int*   ei = (const int*)d_in[2];
  const float* W1 = (const float*)d_in[3];
  const float* b1 = (const float*)d_in[4];
  const float* W2 = (const float*)d_in[5];
  const float* b2 = (const float*)d_in[6];
  const float* W3 = (const float*)d_in[7];
  const float* b3 = (const float*)d_in[8];
  float* out = (float*)d_out;

  char* base = (char*)d_ws;
  size_t off = 0;
  auto take = [&](size_t bytes) -> char* {
    char* p = base + off;
    off += (bytes + 255) & ~(size_t)255;
    return p;
  };

  // CSR region (live for entire call)
  int* dcnt   = (int*)take((size_t)N_NODES * 4);
  int* bcnt   = (int*)take((size_t)N_EDGES * 4);
  int* ncur   = (int*)take((size_t)N_NODES * 4);
  int* ecur   = (int*)take((size_t)N_EDGES * 4);
  int* noff   = (int*)take((size_t)(N_NODES + 1) * 4);
  int* eoff   = (int*)take((size_t)(N_EDGES + 1) * 4);
  int* npart  = (int*)take((size_t)((N_NODES + 255) / 256) * 4);
  int* epart  = (int*)take((size_t)((N_EDGES + 255) / 256) * 4);
  int* nedges = (int*)take((size_t)NNZ * 4);
  int* enodes = (int*)take((size_t)NNZ * 4);
  float* dinv = (float*)take((size_t)N_NODES * 4);
  float* binv = (float*)take((size_t)N_EDGES * 4);

  // W splits (live entire call)
  unsigned short* W1th = (unsigned short*)take((size_t)256 * 128 * 2);
  unsigned short* W1tl = (unsigned short*)take((size_t)256 * 128 * 2);
  unsigned short* W2th = (unsigned short*)take((size_t)256 * 256 * 2);
  unsigned short* W2tl = (unsigned short*)take((size_t)256 * 256 * 2);
  unsigned short* W3th = (unsigned short*)take((size_t)48 * 256 * 2);
  unsigned short* W3tl = (unsigned short*)take((size_t)48 * 256 * 2);

  // Big regions with liveness-based aliasing
  const size_t A2B = (size_t)NPAD * 256 * 2;  // one bf16 [NPAD][256]
  const size_t A1B = (size_t)NPAD * 128 * 2;
  char* R2 = take(2 * A2B);
  char* R3 = take(2 * A2B);

  // R2: [A2h | A2l] (gemm1 out, gemm2 in) -> then m256 in A2l slot, t3+m40 in A2h slot
  unsigned short* A2h = (unsigned short*)R2;
  unsigned short* A2l = (unsigned short*)(R2 + A2B);
  float* m256 = (float*)(R2 + A2B);
  float* t3   = (float*)R2;
  float* m40  = (float*)(R2 + 16015360);

  // R3: [m128 | A1h | A1l] early -> t2 (gemm2 out) -> [A3h | A3l]
  float* m128 = (float*)R3;
  unsigned short* A1h = (unsigned short*)(R3 + 10240000);
  unsigned short* A1l = (unsigned short*)(R3 + 10240000 + A1B);
  float* t2 = (float*)R3;
  unsigned short* A3h = (unsigned short*)R3;
  unsigned short* A3l = (unsigned short*)(R3 + A2B);

  // ---- CSR build ----
  hipMemsetAsync(dcnt, 0, (size_t)N_NODES * 4, stream);
  hipMemsetAsync(bcnt, 0, (size_t)N_EDGES * 4, stream);
  hipMemsetAsync(ncur, 0, (size_t)N_NODES * 4, stream);
  hipMemsetAsync(ecur, 0, (size_t)N_EDGES * 4, stream);

  count_kernel<<<(NNZ + 255) / 256, 256, 0, stream>>>(ni, ei, dcnt, bcnt);
  invert_kernel<<<(N_NODES + 255) / 256, 256, 0, stream>>>(dcnt, dinv, N_NODES);
  invert_kernel<<<(N_EDGES + 255) / 256, 256, 0, stream>>>(bcnt, binv, N_EDGES);

  const int nb_n = (N_NODES + 255) / 256;
  const int nb_e = (N_EDGES + 255) / 256;
  scan_block<256><<<nb_n, 256, 0, stream>>>(dcnt, N_NODES, noff, npart);
  scan_block<256><<<nb_e, 256, 0, stream>>>(bcnt, N_EDGES, eoff, epart);
  scan_partials<<<1, 1024, 0, stream>>>(npart, nb_n, &noff[N_NODES]);
  scan_partials<<<1, 1024, 0, stream>>>(epart, nb_e, &eoff[N_EDGES]);
  scan_add<<<nb_n, 256, 0, stream>>>(noff, N_NODES, npart);
  scan_add<<<nb_e, 256, 0, stream>>>(eoff, N_EDGES, epart);

  fill_kernel<<<(NNZ + 255) / 256, 256, 0, stream>>>(ni, ei, noff, eoff, ncur, ecur, nedges, enodes);

  // ---- W pre-split (transposed) ----
  wsplit_t<<<(256 * 128 + 255) / 256, 256, 0, stream>>>(W1, 128, 256, 256, W1th, W1tl);
  wsplit_t<<<(256 * 256 + 255) / 256, 256, 0, stream>>>(W2, 256, 256, 256, W2th, W2tl);
  wsplit_t<<<(48 * 256 + 255) / 256, 256, 0, stream>>>(W3, 256, 40, 48, W3th, W3tl);

  const int eblocks = (N_EDGES * 64 + 255) / 256;  // 5000
  const int nblocks = (N_NODES * 64 + 255) / 256;  // 25000
  const int gm = NPAD / 128;                       // 782

  // ---- Layer 1: agg = Dinv H Binv H^T x  (F=128), then h1 = elu(agg@W1 + b1) ----
  edge_reduce128<<<eblocks, 256, 0, stream>>>(x, eoff, enodes, binv, m128);
  node_reduce128_split<<<nblocks, 256, 0, stream>>>(m128, noff, nedges, dinv, A1h, A1l);
  gemm_tile<4, 4, 2, 2, 1><<<dim3(gm, 2), 256, 0, stream>>>(
      A1h, A1l, W1th, W1tl, 128, b1, nullptr, A2h, A2l, 256);

  // ---- Layer 2: t2 = h1@W2 ; h2 = elu(Dinv H Binv H^T t2 + b2) ----
  gemm_tile<4, 4, 2, 2, 0><<<dim3(gm, 2), 256, 0, stream>>>(
      A2h, A2l, W2th, W2tl, 256, nullptr, t2, nullptr, nullptr, 256);
  edge_reduce256<<<eblocks, 256, 0, stream>>>(t2, eoff, enodes, binv, m256);
  node_reduce256_split_elu<<<nblocks, 256, 0, stream>>>(m256, noff, nedges, dinv, b2, A3h, A3l);

  // ---- Layer 3: t3 = h2@W3 ; out = Dinv H Binv H^T t3 + b3 ----
  gemm_tile<2, 3, 4, 1, 0><<<dim3(gm, 1), 256, 0, stream>>>(
      A3h, A3l, W3th, W3tl, 256, nullptr, t3, nullptr, nullptr, 40);
  edge_reduce40<<<eblocks, 256, 0, stream>>>(t3, eoff, enodes, binv, m40);
  node_reduce40<<<nblocks, 256, 0, stream>>>(m40, noff, nedges, dinv, b3, out);
}

// Round 6
// 812.919 us; speedup vs baseline: 1.6809x; 1.0936x over previous
//
#include <hip/hip_runtime.h>
#include <cstdint>
#include <cstddef>

constexpr int N_NODES = 100000;
constexpr int N_EDGES = 20000;
constexpr int NNZ     = 1000000;
constexpr int NPAD    = 100096;  // 782 * 128
constexpr int EPAD    = 20096;   // 157 * 128

typedef __attribute__((ext_vector_type(8))) __bf16 bf16x8;
typedef __attribute__((ext_vector_type(4))) float f32x4;

// ---------------- bf16 split helpers (RNE) ----------------
__device__ __forceinline__ unsigned short bf16_rne(float v) {
  unsigned u = __builtin_bit_cast(unsigned, v);
  return (unsigned short)((u + 0x7FFFu + ((u >> 16) & 1u)) >> 16);
}
__device__ __forceinline__ void split2(float v, unsigned short& h, unsigned short& l) {
  unsigned u = __builtin_bit_cast(unsigned, v);
  unsigned hb = (u + 0x7FFFu + ((u >> 16) & 1u)) & 0xFFFF0000u;
  h = (unsigned short)(hb >> 16);
  float lo = v - __builtin_bit_cast(float, hb);
  l = bf16_rne(lo);
}
__device__ __forceinline__ float elu_f(float x) { return x > 0.f ? x : expm1f(x); }

// async global->LDS, 16B per lane; LDS dest is wave-uniform base (+lane*16 by HW)
__device__ __forceinline__ void gload_lds16(const void* g, void* l) {
  __builtin_amdgcn_global_load_lds(
      (const __attribute__((address_space(1))) unsigned int*)(uintptr_t)g,
      (__attribute__((address_space(3))) unsigned int*)(uintptr_t)l, 16, 0, 0);
}

// ---------------- degree counting ----------------
__global__ void count_kernel(const int* __restrict__ ni, const int* __restrict__ ei,
                             int* __restrict__ dcnt, int* __restrict__ bcnt) {
  int i = blockIdx.x * blockDim.x + threadIdx.x;
  if (i < NNZ) {
    atomicAdd(&dcnt[ni[i]], 1);
    atomicAdd(&bcnt[ei[i]], 1);
  }
}

__global__ void invert2_kernel(const int* __restrict__ dcnt, const int* __restrict__ bcnt,
                               float* __restrict__ dinv, float* __restrict__ binv) {
  int i = blockIdx.x * blockDim.x + threadIdx.x;
  if (i < N_NODES) {
    int c = dcnt[i];
    dinv[i] = c > 0 ? 1.0f / (float)c : 0.0f;
  }
  if (i < N_EDGES) {
    int c = bcnt[i];
    binv[i] = c > 0 ? 1.0f / (float)c : 0.0f;
  }
}

// ---------------- fused exclusive scans ----------------
__device__ __forceinline__ void scan_block_body(const int* __restrict__ cnt, int n,
                                                int* __restrict__ out,
                                                int* __restrict__ partials, int bid) {
  __shared__ int buf[256];
  int tid = threadIdx.x;
  int i = bid * 256 + tid;
  int v = (i < n) ? cnt[i] : 0;
  buf[tid] = v;
  __syncthreads();
  for (int o = 1; o < 256; o <<= 1) {
    int t = (tid >= o) ? buf[tid - o] : 0;
    __syncthreads();
    buf[tid] += t;
    __syncthreads();
  }
  if (i < n) out[i] = buf[tid] - v;
  if (tid == 255) partials[bid] = buf[tid];
}

__global__ void scan_block2(const int* __restrict__ c1, int n1, int* __restrict__ o1,
                            int* __restrict__ p1, int nb1,
                            const int* __restrict__ c2, int n2, int* __restrict__ o2,
                            int* __restrict__ p2) {
  if ((int)blockIdx.x < nb1) scan_block_body(c1, n1, o1, p1, blockIdx.x);
  else scan_block_body(c2, n2, o2, p2, blockIdx.x - nb1);
}

__device__ __forceinline__ void scan_partials_body(int* __restrict__ partials, int nb,
                                                   int* __restrict__ total_out) {
  __shared__ int buf[1024];
  int tid = threadIdx.x;
  int v = (tid < nb) ? partials[tid] : 0;
  buf[tid] = v;
  __syncthreads();
  for (int o = 1; o < 1024; o <<= 1) {
    int t = (tid >= o) ? buf[tid - o] : 0;
    __syncthreads();
    buf[tid] += t;
    __syncthreads();
  }
  if (tid < nb) partials[tid] = buf[tid] - v;
  if (tid == 1023) *total_out = buf[1023];
}

__global__ void scan_partials2(int* __restrict__ p1, int nb1, int* __restrict__ t1,
                               int* __restrict__ p2, int nb2, int* __restrict__ t2) {
  if (blockIdx.x == 0) scan_partials_body(p1, nb1, t1);
  else scan_partials_body(p2, nb2, t2);
}

__global__ void scan_add2(int* __restrict__ o1, int n1, const int* __restrict__ p1, int nb1,
                          int* __restrict__ o2, int n2, const int* __restrict__ p2) {
  if ((int)blockIdx.x < nb1) {
    int i = blockIdx.x * 256 + threadIdx.x;
    if (i < n1) o1[i] += p1[blockIdx.x];
  } else {
    int b = blockIdx.x - nb1;
    int i = b * 256 + threadIdx.x;
    if (i < n2) o2[i] += p2[b];
  }
}

// ---------------- CSR fill (atomic cursors) ----------------
__global__ void fill_kernel(const int* __restrict__ ni, const int* __restrict__ ei,
                            const int* __restrict__ noff, const int* __restrict__ eoff,
                            int* __restrict__ ncur, int* __restrict__ ecur,
                            int* __restrict__ nedges, int* __restrict__ enodes) {
  int i = blockIdx.x * blockDim.x + threadIdx.x;
  if (i < NNZ) {
    int n = ni[i], e = ei[i];
    int p = atomicAdd(&ecur[e], 1);
    enodes[eoff[e] + p] = n;
    int q = atomicAdd(&ncur[n], 1);
    nedges[noff[n] + q] = e;
  }
}

// ---------------- fused W split+transpose ----------------
// W1[128][256]->W1t[256][128], W2[256][256]->W2t[256][256], W3[256][40]->W3t[48][256]
__global__ void wsplit_all(const float* __restrict__ W1, const float* __restrict__ W2,
                           const float* __restrict__ W3,
                           unsigned short* __restrict__ W1th, unsigned short* __restrict__ W1tl,
                           unsigned short* __restrict__ W2th, unsigned short* __restrict__ W2tl,
                           unsigned short* __restrict__ W3th, unsigned short* __restrict__ W3tl) {
  int i = blockIdx.x * 256 + threadIdx.x;
  float v;
  unsigned short h, l;
  if (i < 32768) {  // W1t: n = i>>7, k = i&127
    int n = i >> 7, k = i & 127;
    v = W1[(size_t)k * 256 + n];
    split2(v, h, l);
    W1th[i] = h; W1tl[i] = l;
  } else if (i < 98304) {
    int j = i - 32768;
    int n = j >> 8, k = j & 255;
    v = W2[(size_t)k * 256 + n];
    split2(v, h, l);
    W2th[j] = h; W2tl[j] = l;
  } else if (i < 110592) {
    int j = i - 98304;
    int n = j >> 8, k = j & 255;
    v = (n < 40) ? W3[(size_t)k * 40 + n] : 0.0f;
    split2(v, h, l);
    W3th[j] = h; W3tl[j] = l;
  }
}

// ---------------- LDS-staged split-bf16 MFMA GEMM ----------------
// C[M, N] = (Ah+Al)[M,K] @ (Bh+Bl)[K,N], 3-term split, f32 accum.
// LDS tiles: linear [row][64B]; 16B-slot XOR swizzle with the 2 in-row bits:
// colbyte ^= ((row&3)<<4), applied identically to the pre-swizzled global
// source address (rule 21) and the fragment ds_read_b128.
// EPI 0: f32 store (col-masked). EPI 2: v=elu(v+bias[col]) -> f32 store.
template <int MFR, int NFR, int WAVES_M, int WAVES_N, int EPI>
__global__ __launch_bounds__(256) void gemm_tile(
    const unsigned short* __restrict__ Ah, const unsigned short* __restrict__ Al,
    const unsigned short* __restrict__ Bh, const unsigned short* __restrict__ Bl,
    int K, const float* __restrict__ bias, float* __restrict__ outF, int ncols,
    int Mrows) {
  constexpr int BM = WAVES_M * MFR * 16;
  constexpr int BN = WAVES_N * NFR * 16;
  __shared__ char lds[(BM + BN) * 128];
  char* Ash = lds;
  char* Asl = lds + BM * 64;
  char* Bsh = lds + BM * 128;
  char* Bsl = lds + BM * 128 + BN * 64;

  const int wave = threadIdx.x >> 6;
  const int lane = threadIdx.x & 63;
  const int rl = lane & 15;
  const int g = lane >> 4;
  const int wr = wave / WAVES_N;
  const int wc = wave % WAVES_N;
  const int rowbase = blockIdx.x * BM;
  const int colbase = blockIdx.y * BN;

  f32x4 acc[MFR][NFR] = {};

  auto stage = [&](const unsigned short* G, char* S, int R, int rbase, int k0) {
    for (int wi = wave; wi < (R >> 4); wi += 4) {
      int c = wi * 64 + lane;
      int row = c >> 2;
      int colbyte = ((lane & 3) * 16) ^ ((row & 3) << 4);
      const char* src = (const char*)G + ((size_t)(rbase + row) * K + k0) * 2 + colbyte;
      gload_lds16(src, S + wi * 1024);
    }
  };

  for (int k0 = 0; k0 < K; k0 += 32) {
    stage(Ah, Ash, BM, rowbase, k0);
    stage(Al, Asl, BM, rowbase, k0);
    stage(Bh, Bsh, BN, colbase, k0);
    stage(Bl, Bsl, BN, colbase, k0);
    asm volatile("s_waitcnt vmcnt(0)" ::: "memory");
    __syncthreads();

    bf16x8 afh[MFR], afl[MFR], bfh[NFR], bfl[NFR];
#pragma unroll
    for (int mf = 0; mf < MFR; ++mf) {
      int r = wr * MFR * 16 + mf * 16 + rl;
      int addr = r * 64 + ((g * 16) ^ ((r & 3) << 4));
      afh[mf] = *(const bf16x8*)(Ash + addr);
      afl[mf] = *(const bf16x8*)(Asl + addr);
    }
#pragma unroll
    for (int nf = 0; nf < NFR; ++nf) {
      int r = wc * NFR * 16 + nf * 16 + rl;
      int addr = r * 64 + ((g * 16) ^ ((r & 3) << 4));
      bfh[nf] = *(const bf16x8*)(Bsh + addr);
      bfl[nf] = *(const bf16x8*)(Bsl + addr);
    }
#pragma unroll
    for (int mf = 0; mf < MFR; ++mf)
#pragma unroll
      for (int nf = 0; nf < NFR; ++nf) {
        acc[mf][nf] = __builtin_amdgcn_mfma_f32_16x16x32_bf16(afh[mf], bfh[nf], acc[mf][nf], 0, 0, 0);
        acc[mf][nf] = __builtin_amdgcn_mfma_f32_16x16x32_bf16(afh[mf], bfl[nf], acc[mf][nf], 0, 0, 0);
        acc[mf][nf] = __builtin_amdgcn_mfma_f32_16x16x32_bf16(afl[mf], bfh[nf], acc[mf][nf], 0, 0, 0);
      }
    __syncthreads();
  }

#pragma unroll
  for (int mf = 0; mf < MFR; ++mf)
#pragma unroll
    for (int nf = 0; nf < NFR; ++nf)
#pragma unroll
      for (int i = 0; i < 4; ++i) {
        int grow = rowbase + wr * MFR * 16 + mf * 16 + g * 4 + i;
        if (grow >= Mrows) continue;
        int gcol = colbase + wc * NFR * 16 + nf * 16 + rl;
        if (gcol >= ncols) continue;
        float v = acc[mf][nf][i];
        if (EPI == 2) {
          v += bias[gcol];
          v = elu_f(v);
        }
        outF[(size_t)grow * ncols + gcol] = v;
      }
}

// ---------------- segment reductions (4x unrolled, 4 independent accumulators) ----------------
#define ACC4(a, v) { a.x += v.x; a.y += v.y; a.z += v.z; a.w += v.w; }

// edge gather at F=256 from h1, scale by Binv, split -> hi/lo bf16 planes.
// Launched over EPAD segments; rows >= N_EDGES write zeros (pad for gemm2).
__global__ __launch_bounds__(256) void edge_reduce256_split(
    const float* __restrict__ h1, const int* __restrict__ eoff,
    const int* __restrict__ enodes, const float* __restrict__ binv,
    unsigned short* __restrict__ mh, unsigned short* __restrict__ ml) {
  int w = (blockIdx.x * blockDim.x + threadIdx.x) >> 6;
  int lane = threadIdx.x & 63;
  if (w >= EPAD) return;
  if (w >= N_EDGES) {
    uint2 z = {0, 0};
    *reinterpret_cast<uint2*>(&mh[(size_t)w * 256 + lane * 4]) = z;
    *reinterpret_cast<uint2*>(&ml[(size_t)w * 256 + lane * 4]) = z;
    return;
  }
  int s = eoff[w], t = eoff[w + 1];
  float4 a0 = {0, 0, 0, 0}, a1 = {0, 0, 0, 0}, a2 = {0, 0, 0, 0}, a3 = {0, 0, 0, 0};
  int j = s;
  for (; j < t && (j & 3); ++j) {
    float4 v = *reinterpret_cast<const float4*>(&h1[(size_t)enodes[j] * 256 + lane * 4]);
    ACC4(a0, v);
  }
  for (; j + 4 <= t; j += 4) {
    int4 idx = *reinterpret_cast<const int4*>(enodes + j);
    float4 v0 = *reinterpret_cast<const float4*>(&h1[(size_t)idx.x * 256 + lane * 4]);
    float4 v1 = *reinterpret_cast<const float4*>(&h1[(size_t)idx.y * 256 + lane * 4]);
    float4 v2 = *reinterpret_cast<const float4*>(&h1[(size_t)idx.z * 256 + lane * 4]);
    float4 v3 = *reinterpret_cast<const float4*>(&h1[(size_t)idx.w * 256 + lane * 4]);
    ACC4(a0, v0); ACC4(a1, v1); ACC4(a2, v2); ACC4(a3, v3);
  }
  for (; j < t; ++j) {
    float4 v = *reinterpret_cast<const float4*>(&h1[(size_t)enodes[j] * 256 + lane * 4]);
    ACC4(a0, v);
  }
  float bv = binv[w];
  float v0 = (a0.x + a1.x + a2.x + a3.x) * bv;
  float v1 = (a0.y + a1.y + a2.y + a3.y) * bv;
  float v2 = (a0.z + a1.z + a2.z + a3.z) * bv;
  float v3 = (a0.w + a1.w + a2.w + a3.w) * bv;
  unsigned short h0, l0, h1s, l1, h2, l2, h3, l3;
  split2(v0, h0, l0);
  split2(v1, h1s, l1);
  split2(v2, h2, l2);
  split2(v3, h3, l3);
  uint2 ph, pl;
  ph.x = (unsigned)h0 | ((unsigned)h1s << 16);
  ph.y = (unsigned)h2 | ((unsigned)h3 << 16);
  pl.x = (unsigned)l0 | ((unsigned)l1 << 16);
  pl.y = (unsigned)l2 | ((unsigned)l3 << 16);
  *reinterpret_cast<uint2*>(&mh[(size_t)w * 256 + lane * 4]) = ph;
  *reinterpret_cast<uint2*>(&ml[(size_t)w * 256 + lane * 4]) = pl;
}

__global__ __launch_bounds__(256) void node_reduce256_split_elu(
    const float* __restrict__ m, const int* __restrict__ noff,
    const int* __restrict__ nedges, const float* __restrict__ dinv,
    const float* __restrict__ bias, unsigned short* __restrict__ Ah,
    unsigned short* __restrict__ Al) {
  int w = (blockIdx.x * blockDim.x + threadIdx.x) >> 6;
  int lane = threadIdx.x & 63;
  if (w >= N_NODES) return;
  int s = noff[w], t = noff[w + 1];
  float4 a0 = {0, 0, 0, 0}, a1 = {0, 0, 0, 0}, a2 = {0, 0, 0, 0}, a3 = {0, 0, 0, 0};
  int j = s;
  for (; j < t && (j & 3); ++j) {
    float4 v = *reinterpret_cast<const float4*>(&m[(size_t)nedges[j] * 256 + lane * 4]);
    ACC4(a0, v);
  }
  for (; j + 4 <= t; j += 4) {
    int4 idx = *reinterpret_cast<const int4*>(nedges + j);
    float4 v0 = *reinterpret_cast<const float4*>(&m[(size_t)idx.x * 256 + lane * 4]);
    float4 v1 = *reinterpret_cast<const float4*>(&m[(size_t)idx.y * 256 + lane * 4]);
    float4 v2 = *reinterpret_cast<const float4*>(&m[(size_t)idx.z * 256 + lane * 4]);
    float4 v3 = *reinterpret_cast<const float4*>(&m[(size_t)idx.w * 256 + lane * 4]);
    ACC4(a0, v0); ACC4(a1, v1); ACC4(a2, v2); ACC4(a3, v3);
  }
  for (; j < t; ++j) {
    float4 v = *reinterpret_cast<const float4*>(&m[(size_t)nedges[j] * 256 + lane * 4]);
    ACC4(a0, v);
  }
  float dv = dinv[w];
  float4 b4 = *reinterpret_cast<const float4*>(&bias[lane * 4]);
  float v0 = elu_f((a0.x + a1.x + a2.x + a3.x) * dv + b4.x);
  float v1 = elu_f((a0.y + a1.y + a2.y + a3.y) * dv + b4.y);
  float v2 = elu_f((a0.z + a1.z + a2.z + a3.z) * dv + b4.z);
  float v3 = elu_f((a0.w + a1.w + a2.w + a3.w) * dv + b4.w);
  unsigned short h0, l0, h1, l1, h2, l2, h3, l3;
  split2(v0, h0, l0);
  split2(v1, h1, l1);
  split2(v2, h2, l2);
  split2(v3, h3, l3);
  uint2 ph, pl;
  ph.x = (unsigned)h0 | ((unsigned)h1 << 16);
  ph.y = (unsigned)h2 | ((unsigned)h3 << 16);
  pl.x = (unsigned)l0 | ((unsigned)l1 << 16);
  pl.y = (unsigned)l2 | ((unsigned)l3 << 16);
  *reinterpret_cast<uint2*>(&Ah[(size_t)w * 256 + lane * 4]) = ph;
  *reinterpret_cast<uint2*>(&Al[(size_t)w * 256 + lane * 4]) = pl;
}

__global__ __launch_bounds__(256) void edge_reduce128(const float* __restrict__ x,
                                                      const int* __restrict__ eoff,
                                                      const int* __restrict__ enodes,
                                                      const float* __restrict__ binv,
                                                      float* __restrict__ m) {
  int w = (blockIdx.x * blockDim.x + threadIdx.x) >> 6;
  int lane = threadIdx.x & 63;
  if (w >= N_EDGES) return;
  int s = eoff[w], t = eoff[w + 1];
  float2 a0 = {0, 0}, a1 = {0, 0}, a2 = {0, 0}, a3 = {0, 0};
  int j = s;
  for (; j < t && (j & 3); ++j) {
    float2 v = *reinterpret_cast<const float2*>(&x[(size_t)enodes[j] * 128 + lane * 2]);
    a0.x += v.x; a0.y += v.y;
  }
  for (; j + 4 <= t; j += 4) {
    int4 idx = *reinterpret_cast<const int4*>(enodes + j);
    float2 v0 = *reinterpret_cast<const float2*>(&x[(size_t)idx.x * 128 + lane * 2]);
    float2 v1 = *reinterpret_cast<const float2*>(&x[(size_t)idx.y * 128 + lane * 2]);
    float2 v2 = *reinterpret_cast<const float2*>(&x[(size_t)idx.z * 128 + lane * 2]);
    float2 v3 = *reinterpret_cast<const float2*>(&x[(size_t)idx.w * 128 + lane * 2]);
    a0.x += v0.x; a0.y += v0.y;
    a1.x += v1.x; a1.y += v1.y;
    a2.x += v2.x; a2.y += v2.y;
    a3.x += v3.x; a3.y += v3.y;
  }
  for (; j < t; ++j) {
    float2 v = *reinterpret_cast<const float2*>(&x[(size_t)enodes[j] * 128 + lane * 2]);
    a0.x += v.x; a0.y += v.y;
  }
  float bv = binv[w];
  float2 r;
  r.x = (a0.x + a1.x + a2.x + a3.x) * bv;
  r.y = (a0.y + a1.y + a2.y + a3.y) * bv;
  *reinterpret_cast<float2*>(&m[(size_t)w * 128 + lane * 2]) = r;
}

__global__ __launch_bounds__(256) void node_reduce128_split(const float* __restrict__ m,
                                                            const int* __restrict__ noff,
                                                            const int* __restrict__ nedges,
                                                            const float* __restrict__ dinv,
                                                            unsigned short* __restrict__ Ah,
                                                            unsigned short* __restrict__ Al) {
  int w = (blockIdx.x * blockDim.x + threadIdx.x) >> 6;
  int lane = threadIdx.x & 63;
  if (w >= N_NODES) return;
  int s = noff[w], t = noff[w + 1];
  float2 a0 = {0, 0}, a1 = {0, 0}, a2 = {0, 0}, a3 = {0, 0};
  int j = s;
  for (; j < t && (j & 3); ++j) {
    float2 v = *reinterpret_cast<const float2*>(&m[(size_t)nedges[j] * 128 + lane * 2]);
    a0.x += v.x; a0.y += v.y;
  }
  for (; j + 4 <= t; j += 4) {
    int4 idx = *reinterpret_cast<const int4*>(nedges + j);
    float2 v0 = *reinterpret_cast<const float2*>(&m[(size_t)idx.x * 128 + lane * 2]);
    float2 v1 = *reinterpret_cast<const float2*>(&m[(size_t)idx.y * 128 + lane * 2]);
    float2 v2 = *reinterpret_cast<const float2*>(&m[(size_t)idx.z * 128 + lane * 2]);
    float2 v3 = *reinterpret_cast<const float2*>(&m[(size_t)idx.w * 128 + lane * 2]);
    a0.x += v0.x; a0.y += v0.y;
    a1.x += v1.x; a1.y += v1.y;
    a2.x += v2.x; a2.y += v2.y;
    a3.x += v3.x; a3.y += v3.y;
  }
  for (; j < t; ++j) {
    float2 v = *reinterpret_cast<const float2*>(&m[(size_t)nedges[j] * 128 + lane * 2]);
    a0.x += v.x; a0.y += v.y;
  }
  float dv = dinv[w];
  float ax = (a0.x + a1.x + a2.x + a3.x) * dv;
  float ay = (a0.y + a1.y + a2.y + a3.y) * dv;
  unsigned short h0, l0, h1, l1;
  split2(ax, h0, l0);
  split2(ay, h1, l1);
  unsigned ph = (unsigned)h0 | ((unsigned)h1 << 16);
  unsigned pl = (unsigned)l0 | ((unsigned)l1 << 16);
  *reinterpret_cast<unsigned*>(&Ah[(size_t)w * 128 + lane * 2]) = ph;
  *reinterpret_cast<unsigned*>(&Al[(size_t)w * 128 + lane * 2]) = pl;
}

__global__ __launch_bounds__(256) void edge_reduce40(const float* __restrict__ xw,
                                                     const int* __restrict__ eoff,
                                                     const int* __restrict__ enodes,
                                                     const float* __restrict__ binv,
                                                     float* __restrict__ m) {
  int w = (blockIdx.x * blockDim.x + threadIdx.x) >> 6;
  int lane = threadIdx.x & 63;
  if (w >= N_EDGES || lane >= 40) return;
  int s = eoff[w], t = eoff[w + 1];
  float a0 = 0.f, a1 = 0.f, a2 = 0.f, a3 = 0.f;
  int j = s;
  for (; j < t && (j & 3); ++j) a0 += xw[(size_t)enodes[j] * 40 + lane];
  for (; j + 4 <= t; j += 4) {
    int4 idx = *reinterpret_cast<const int4*>(enodes + j);
    a0 += xw[(size_t)idx.x * 40 + lane];
    a1 += xw[(size_t)idx.y * 40 + lane];
    a2 += xw[(size_t)idx.z * 40 + lane];
    a3 += xw[(size_t)idx.w * 40 + lane];
  }
  for (; j < t; ++j) a0 += xw[(size_t)enodes[j] * 40 + lane];
  m[(size_t)w * 40 + lane] = (a0 + a1 + a2 + a3) * binv[w];
}

__global__ __launch_bounds__(256) void node_reduce40(const float* __restrict__ m,
                                                     const int* __restrict__ noff,
                                                     const int* __restrict__ nedges,
                                                     const float* __restrict__ dinv,
                                                     const float* __restrict__ bias,
                                                     float* __restrict__ out) {
  int w = (blockIdx.x * blockDim.x + threadIdx.x) >> 6;
  int lane = threadIdx.x & 63;
  if (w >= N_NODES || lane >= 40) return;
  int s = noff[w], t = noff[w + 1];
  float a0 = 0.f, a1 = 0.f, a2 = 0.f, a3 = 0.f;
  int j = s;
  for (; j < t && (j & 3); ++j) a0 += m[(size_t)nedges[j] * 40 + lane];
  for (; j + 4 <= t; j += 4) {
    int4 idx = *reinterpret_cast<const int4*>(nedges + j);
    a0 += m[(size_t)idx.x * 40 + lane];
    a1 += m[(size_t)idx.y * 40 + lane];
    a2 += m[(size_t)idx.z * 40 + lane];
    a3 += m[(size_t)idx.w * 40 + lane];
  }
  for (; j < t; ++j) a0 += m[(size_t)nedges[j] * 40 + lane];
  out[(size_t)w * 40 + lane] = (a0 + a1 + a2 + a3) * dinv[w] + bias[lane];
}

// ---------------- launch ----------------
extern "C" void kernel_launch(void* const* d_in, const int* in_sizes, int n_in,
                              void* d_out, int out_size, void* d_ws, size_t ws_size,
                              hipStream_t stream) {
  const float* x  = (const float*)d_in[0];
  const int*   ni = (const int*)d_in[1];
  const int*   ei = (const int*)d_in[2];
  const float* W1 = (const float*)d_in[3];
  const float* b1 = (const float*)d_in[4];
  const float* W2 = (const float*)d_in[5];
  const float* b2 = (const float*)d_in[6];
  const float* W3 = (const float*)d_in[7];
  const float* b3 = (const float*)d_in[8];
  float* out = (float*)d_out;

  char* base = (char*)d_ws;
  size_t off = 0;
  auto take = [&](size_t bytes) -> char* {
    char* p = base + off;
    off += (bytes + 255) & ~(size_t)255;
    return p;
  };

  // CSR region (dcnt..ecur contiguous for single memset)
  int* dcnt   = (int*)take((size_t)N_NODES * 4);   // 400128
  int* bcnt   = (int*)take((size_t)N_EDGES * 4);   // 80128
  int* ncur   = (int*)take((size_t)N_NODES * 4);   // 400128
  int* ecur   = (int*)take((size_t)N_EDGES * 4);   // 80128
  const size_t memset_span = 400128 + 80128 + 400128 + 80128;
  int* noff   = (int*)take((size_t)(N_NODES + 1) * 4);
  int* eoff   = (int*)take((size_t)(N_EDGES + 1) * 4);
  int* npart  = (int*)take((size_t)((N_NODES + 255) / 256) * 4);
  int* epart  = (int*)take((size_t)((N_EDGES + 255) / 256) * 4);
  int* nedges = (int*)take((size_t)NNZ * 4);
  int* enodes = (int*)take((size_t)NNZ * 4);
  float* dinv = (float*)take((size_t)N_NODES * 4);
  float* binv = (float*)take((size_t)N_EDGES * 4);

  // W splits (live entire call)
  unsigned short* W1th = (unsigned short*)take((size_t)256 * 128 * 2);
  unsigned short* W1tl = (unsigned short*)take((size_t)256 * 128 * 2);
  unsigned short* W2th = (unsigned short*)take((size_t)256 * 256 * 2);
  unsigned short* W2tl = (unsigned short*)take((size_t)256 * 256 * 2);
  unsigned short* W3th = (unsigned short*)take((size_t)48 * 256 * 2);
  unsigned short* W3tl = (unsigned short*)take((size_t)48 * 256 * 2);

  // Big regions with liveness-based aliasing
  const size_t A2B = (size_t)NPAD * 256 * 2;  // 51,249,152
  char* R2 = take(2 * A2B);  // h1 f32 -> A3h | A3l
  char* R3 = take(2 * A2B);  // m128|A1h|A1l -> m2eh|m2el|m256f -> t3|m40

  float* h1 = (float*)R2;
  unsigned short* A3h = (unsigned short*)R2;
  unsigned short* A3l = (unsigned short*)(R2 + A2B);

  float* m128 = (float*)R3;                                      // 10.24 MB
  unsigned short* A1h = (unsigned short*)(R3 + 10240000);
  unsigned short* A1l = (unsigned short*)(R3 + 10240000 + (size_t)NPAD * 128 * 2);

  const size_t MEB = (size_t)EPAD * 256 * 2;  // 10,289,152
  unsigned short* m2eh = (unsigned short*)R3;
  unsigned short* m2el = (unsigned short*)(R3 + MEB);
  float* m256f = (float*)(R3 + 2 * MEB);                         // 20.48 MB

  float* t3  = (float*)R3;                                       // 16 MB
  float* m40 = (float*)(R3 + 16015360);                          // 3.2 MB

  // ---- CSR build ----
  hipMemsetAsync(dcnt, 0, memset_span, stream);
  count_kernel<<<(NNZ + 255) / 256, 256, 0, stream>>>(ni, ei, dcnt, bcnt);
  invert2_kernel<<<(N_NODES + 255) / 256, 256, 0, stream>>>(dcnt, bcnt, dinv, binv);

  const int nb_n = (N_NODES + 255) / 256;  // 391
  const int nb_e = (N_EDGES + 255) / 256;  // 79
  scan_block2<<<nb_n + nb_e, 256, 0, stream>>>(dcnt, N_NODES, noff, npart, nb_n,
                                               bcnt, N_EDGES, eoff, epart);
  scan_partials2<<<2, 1024, 0, stream>>>(npart, nb_n, &noff[N_NODES],
                                         epart, nb_e, &eoff[N_EDGES]);
  scan_add2<<<nb_n + nb_e, 256, 0, stream>>>(noff, N_NODES, npart, nb_n,
                                             eoff, N_EDGES, epart);
  fill_kernel<<<(NNZ + 255) / 256, 256, 0, stream>>>(ni, ei, noff, eoff, ncur, ecur, nedges, enodes);

  // ---- W pre-split (fused) ----
  wsplit_all<<<(110592 + 255) / 256, 256, 0, stream>>>(W1, W2, W3, W1th, W1tl,
                                                       W2th, W2tl, W3th, W3tl);

  const int eblocks  = (N_EDGES * 64 + 255) / 256;  // 5000
  const int epblocks = (EPAD * 64 + 255) / 256;     // 5024
  const int nblocks  = (N_NODES * 64 + 255) / 256;  // 25000
  const int gm  = NPAD / 128;                       // 782
  const int gme = EPAD / 128;                       // 157

  // ---- Layer 1: agg = Dinv H Binv H^T x (F=128); h1 = elu(agg@W1 + b1) [f32] ----
  edge_reduce128<<<eblocks, 256, 0, stream>>>(x, eoff, enodes, binv, m128);
  node_reduce128_split<<<nblocks, 256, 0, stream>>>(m128, noff, nedges, dinv, A1h, A1l);
  gemm_tile<4, 4, 2, 2, 2><<<dim3(gm, 2), 256, 0, stream>>>(
      A1h, A1l, W1th, W1tl, 128, b1, h1, 256, N_NODES);

  // ---- Layer 2 (reordered): m2e = Binv H^T h1 ; m256f = m2e@W2 ;
  //      h2 = elu(Dinv H m256f + b2) -> split A3 ----
  edge_reduce256_split<<<epblocks, 256, 0, stream>>>(h1, eoff, enodes, binv, m2eh, m2el);
  gemm_tile<4, 4, 2, 2, 0><<<dim3(gme, 2), 256, 0, stream>>>(
      m2eh, m2el, W2th, W2tl, 256, nullptr, m256f, 256, N_EDGES);
  node_reduce256_split_elu<<<nblocks, 256, 0, stream>>>(m256f, noff, nedges, dinv, b2, A3h, A3l);

  // ---- Layer 3: t3 = h2@W3 ; out = Dinv H Binv H^T t3 + b3 ----
  gemm_tile<2, 3, 4, 1, 0><<<dim3(gm, 1), 256, 0, stream>>>(
      A3h, A3l, W3th, W3tl, 256, nullptr, t3, 40, N_NODES);
  edge_reduce40<<<eblocks, 256, 0, stream>>>(t3, eoff, enodes, binv, m40);
  node_reduce40<<<nblocks, 256, 0, stream>>>(m40, noff, nedges, dinv, b3, out);
}